// Round 5
// baseline (402.528 us; speedup 1.0000x reference)
//
#include <hip/hip_runtime.h>

// ChebNet round 20: consolidation + discriminating experiment.
// (1) Revert R19 prop split (cost +12.8us = ~3.2us/dispatch, measured).
// (2) Fuse bscan into bhist (last-block-done ticket + threadfence; NB=196<=256).
// (3) GEMM kernels: A-tiles staged into padded LDS ([3][64][72], 144B stride,
//     conflict-free ds_read_b128) via coalesced 16B/lane loads. Discriminates
//     "codegen never pipelines per-lane fragment loads" (a) vs "fixed
//     per-dispatch overhead" (b): (a) -> total ~335, (b) -> total ~380.
// Props + bucket2 + k_local byte-identical (controls).

typedef unsigned short ushort_t;
typedef __attribute__((ext_vector_type(8))) short v8s;
typedef __attribute__((ext_vector_type(4))) float v4f;

__device__ inline ushort_t f2bf(float f) {  // RNE float->bf16
    unsigned u = __float_as_uint(f);
    return (ushort_t)((u + 0x7FFFu + ((u >> 16) & 1u)) >> 16);
}
__device__ inline float bf2f(ushort_t h) {
    return __uint_as_float(((unsigned)h) << 16);
}

#define BSH 9
#define BSZ (1 << BSH)
#define CHUNK 4096

// ---------- weight prep + gbase/done zeroing (one dispatch) ----------
__global__ void k_wprep(const float* __restrict__ W1, const float* __restrict__ W2,
                        const float* __restrict__ Wm1, const float* __restrict__ Wm2,
                        ushort_t* __restrict__ W1t, ushort_t* __restrict__ W2t,
                        ushort_t* __restrict__ Wm1t, ushort_t* __restrict__ Wm2t,
                        int* __restrict__ gbase, int* __restrict__ done, int NB) {
    int i = blockIdx.x * 256 + threadIdx.x;
    if (i < 12288) { int k = i >> 6, n = i & 63; W1t[n * 192 + k] = f2bf(W1[i]); return; }
    i -= 12288;
    if (i < 12288) { int k = i >> 6, n = i & 63; W2t[n * 192 + k] = f2bf(W2[i]); return; }
    i -= 12288;
    if (i < 4096) { int k = i >> 6, n = i & 63; Wm1t[n * 64 + k] = f2bf(Wm1[i]); return; }
    i -= 4096;
    if (i < 2048) { int k = i >> 5, n = i & 31; Wm2t[n * 64 + k] = f2bf(Wm2[i]); return; }
    i -= 2048;
    if (i < NB) gbase[i] = 0;
    if (i == NB) *done = 0;
}

// ---------- CSR build: hist + fused scan (last-block-done) ----------
__global__ __launch_bounds__(256) void k_bhist(const int* __restrict__ dst,
                                               int* __restrict__ gbase,
                                               int* __restrict__ gcur,
                                               int* __restrict__ done, int E, int NB) {
    __shared__ int h[1024];
    __shared__ int isLast;
    for (int i = threadIdx.x; i < NB; i += 256) h[i] = 0;
    __syncthreads();
    for (int i = blockIdx.x * blockDim.x + threadIdx.x; i < E; i += gridDim.x * blockDim.x)
        atomicAdd(&h[dst[i] >> BSH], 1);
    __syncthreads();
    for (int i = threadIdx.x; i < NB; i += 256)
        if (h[i]) atomicAdd(&gbase[i], h[i]);
    __threadfence();  // each thread: its gbase atomics visible device-wide
    __syncthreads();
    if (threadIdx.x == 0) isLast = (atomicAdd(done, 1) == (int)gridDim.x - 1);
    __syncthreads();
    if (isLast) {
        __threadfence();  // acquire: see all blocks' gbase contributions
        int t = threadIdx.x;
        int v = (t < NB) ? gbase[t] : 0;  // NB (=196) <= 256
        h[t] = v;
        __syncthreads();
        for (int off = 1; off < 256; off <<= 1) {
            int u = (t >= off) ? h[t - off] : 0;
            __syncthreads();
            h[t] += u;
            __syncthreads();
        }
        if (t < NB) {
            int excl = h[t] - v;
            gbase[t] = excl;
            gcur[t] = excl;
        }
    }
}

__global__ __launch_bounds__(256) void k_bucket2(
    const int* __restrict__ src, const int* __restrict__ dst,
    int* __restrict__ gcur, int2* __restrict__ eb, int E, int NB) {
    __shared__ int ls[CHUNK];
    __shared__ int ld[CHUNK];
    __shared__ int hist[1024];
    __shared__ int bbase[1024];
    int t = threadIdx.x;
    int base = blockIdx.x * CHUNK;
    int count = E - base;
    if (count > CHUNK) count = CHUNK;
    for (int i = t; i < NB; i += 256) hist[i] = 0;
    __syncthreads();
    for (int i = t; i < count; i += 256) {
        int s = src[base + i];
        int d = dst[base + i];
        ls[i] = s;
        ld[i] = d;
        atomicAdd(&hist[d >> BSH], 1);
    }
    __syncthreads();
    for (int b = t; b < NB; b += 256) {
        int c = hist[b];
        bbase[b] = c ? atomicAdd(&gcur[b], c) : 0;
        hist[b] = 0;
    }
    __syncthreads();
    for (int i = t; i < count; i += 256) {
        int d = ld[i];
        int b = d >> BSH;
        int off = atomicAdd(&hist[b], 1);
        eb[bbase[b] + off] = make_int2(ls[i], d);
    }
}

__global__ __launch_bounds__(256) void k_local(
    const int2* __restrict__ eb, const int* __restrict__ gbase,
    int* __restrict__ col, int* __restrict__ row_ptr,
    float* __restrict__ dinv, int N, int E, int NB) {
    __shared__ int cnt[BSZ];
    __shared__ int tsum[256];
    int t = threadIdx.x;
    int b = blockIdx.x;
    int d0 = b << BSH;
    cnt[2 * t] = 0;
    cnt[2 * t + 1] = 0;
    __syncthreads();
    int beg = gbase[b];
    int end = (b + 1 < NB) ? gbase[b + 1] : E;
    for (int i = beg + t; i < end; i += 256)
        atomicAdd(&cnt[eb[i].y - d0], 1);
    __syncthreads();
    int c0 = cnt[2 * t], c1 = cnt[2 * t + 1];
    int mysum = c0 + c1;
    tsum[t] = mysum;
    __syncthreads();
    for (int off = 1; off < 256; off <<= 1) {
        int u = 0;
        if (t >= off) u = tsum[t - off];
        __syncthreads();
        tsum[t] += u;
        __syncthreads();
    }
    int rbase = beg + tsum[t] - mysum;
    int d = d0 + 2 * t;
    if (d < N) {
        row_ptr[d] = rbase;
        dinv[d] = rsqrtf(fmaxf((float)c0, 1.0f));
    }
    if (d + 1 < N) {
        row_ptr[d + 1] = rbase + c0;
        dinv[d + 1] = rsqrtf(fmaxf((float)c1, 1.0f));
    }
    cnt[2 * t] = rbase;
    cnt[2 * t + 1] = rbase + c0;
    __syncthreads();
    for (int i = beg + t; i < end; i += 256) {
        int2 e = eb[i];
        int p = atomicAdd(&cnt[e.y - d0], 1);
        col[p] = e.x;
    }
    if (b == NB - 1 && t == 0) row_ptr[N] = E;
}

// ---------- fp32 -> scaled bf16 shadow (standalone, wide grid) ----------
__global__ void k_tobf16(const float4* __restrict__ X, const float* __restrict__ dinv,
                         ushort4* __restrict__ Y, int n4) {
    int i = blockIdx.x * blockDim.x + threadIdx.x;
    if (i < n4) {
        float s = dinv[i >> 4];
        float4 v = X[i];
        ushort4 o;
        o.x = f2bf(v.x * s); o.y = f2bf(v.y * s); o.z = f2bf(v.z * s); o.w = f2bf(v.w * s);
        Y[i] = o;
    }
}

// ---------- propagation (R18 form, unsplit, pinned at fabric ceiling: CONTROL) ----------
template <int MODE>
__global__ __launch_bounds__(256) void k_prop(
    const ushort_t* __restrict__ Xb, const int* __restrict__ rp,
    const int* __restrict__ col, const float* __restrict__ dinv,
    const ushort_t* __restrict__ X0b, ushort_t* __restrict__ OUTB, int N) {
    int wid = (blockIdx.x * blockDim.x + threadIdx.x) >> 6;
    int lane = threadIdx.x & 63;
    if (wid >= N) return;
    int g = lane >> 4;
    int fl = (lane & 15) * 4;
    int beg = rp[wid], end = rp[wid + 1];
    float4 a0 = make_float4(0.f, 0.f, 0.f, 0.f);
    float4 a1 = make_float4(0.f, 0.f, 0.f, 0.f);
    int e = beg + g;
    for (; e + 4 < end; e += 8) {
        int s0 = col[e], s1 = col[e + 4];
        ushort4 u0 = *(const ushort4*)&Xb[(size_t)s0 * 64 + fl];
        ushort4 u1 = *(const ushort4*)&Xb[(size_t)s1 * 64 + fl];
        a0.x += bf2f(u0.x); a0.y += bf2f(u0.y); a0.z += bf2f(u0.z); a0.w += bf2f(u0.w);
        a1.x += bf2f(u1.x); a1.y += bf2f(u1.y); a1.z += bf2f(u1.z); a1.w += bf2f(u1.w);
    }
    if (e < end) {
        int s0 = col[e];
        ushort4 u0 = *(const ushort4*)&Xb[(size_t)s0 * 64 + fl];
        a0.x += bf2f(u0.x); a0.y += bf2f(u0.y); a0.z += bf2f(u0.z); a0.w += bf2f(u0.w);
    }
    float4 acc;
    acc.x = a0.x + a1.x;
    acc.y = a0.y + a1.y;
    acc.z = a0.z + a1.z;
    acc.w = a0.w + a1.w;
    acc.x += __shfl_xor(acc.x, 16);
    acc.y += __shfl_xor(acc.y, 16);
    acc.z += __shfl_xor(acc.z, 16);
    acc.w += __shfl_xor(acc.w, 16);
    acc.x += __shfl_xor(acc.x, 32);
    acc.y += __shfl_xor(acc.y, 32);
    acc.z += __shfl_xor(acc.z, 32);
    acc.w += __shfl_xor(acc.w, 32);
    if (g == 0) {
        float di = dinv[wid];
        ushort4 ob;
        if (MODE == 1) {
            float m = -di * di;
            ob.x = f2bf(m * acc.x);
            ob.y = f2bf(m * acc.y);
            ob.z = f2bf(m * acc.z);
            ob.w = f2bf(m * acc.w);
        } else {
            ushort4 x0u = *(const ushort4*)&X0b[(size_t)wid * 64 + fl];
            float m = -2.0f * di;
            float rd = 1.0f / di;
            ob.x = f2bf(fmaf(m, acc.x, -rd * bf2f(x0u.x)));
            ob.y = f2bf(fmaf(m, acc.y, -rd * bf2f(x0u.y)));
            ob.z = f2bf(fmaf(m, acc.z, -rd * bf2f(x0u.z)));
            ob.w = f2bf(fmaf(m, acc.w, -rd * bf2f(x0u.w)));
        }
        *(ushort4*)&OUTB[(size_t)wid * 64 + fl] = ob;
    }
}

// ---------- cheb linear via MFMA (layer 1, LDS-staged A-tiles) ----------
// A-tile (64 nodes x 3 arrays x 64 cols) staged cooperatively: coalesced 16B/lane
// global loads -> LDS [3][64][72] (144B row stride: conflict-free b128 reads).
template <bool SCALE_OUT>
__global__ __launch_bounds__(256, 4) void k_cheb_mfma(
    const ushort_t* __restrict__ X0, const ushort_t* __restrict__ X1,
    const ushort_t* __restrict__ X2, const float* __restrict__ dinv,
    const ushort_t* __restrict__ Wt, const float* __restrict__ b,
    ushort_t* __restrict__ Yb, int N) {
    __shared__ ushort_t XA[3][64][72];
    int tid = threadIdx.x;
    int node0 = blockIdx.x * 64;
    const ushort_t* Xc[3] = {X0, X1, X2};
    // stage: per array, 2 passes of 256 threads x 8 shorts (coalesced 1KB/wave).
    // Rows beyond N read garbage from adjacent ws arrays (guarded at output).
#pragma unroll
    for (int c = 0; c < 3; c++) {
#pragma unroll
        for (int p = 0; p < 2; p++) {
            int s = p * 2048 + tid * 8;
            int row = s >> 6, cc = s & 63;
            v8s v = *(const v8s*)&Xc[c][((size_t)(node0 + row)) * 64 + cc];
            *(v8s*)&XA[c][row][cc] = v;
        }
    }
    __syncthreads();

    int wave = tid >> 6, lane = tid & 63;
    int n16 = lane & 15, q = lane >> 4;
    int lrow = wave * 16 + n16;
    v8s av[6];
#pragma unroll
    for (int ks = 0; ks < 6; ks++)
        av[ks] = *(const v8s*)&XA[ks >> 1][lrow][(ks & 1) * 32 + q * 8];

    v4f acc_s[4], acc_u[4];
#pragma unroll
    for (int t = 0; t < 4; t++) {
        acc_s[t] = (v4f){0.f, 0.f, 0.f, 0.f};
        acc_u[t] = (v4f){0.f, 0.f, 0.f, 0.f};
    }
#pragma unroll
    for (int ks = 0; ks < 6; ks++) {
        int c = ks >> 1;
#pragma unroll
        for (int t = 0; t < 4; t++) {
            v8s bv = *(const v8s*)&Wt[(size_t)(t * 16 + n16) * 192 + ks * 32 + q * 8];
            if (c < 2)
                acc_s[t] = __builtin_amdgcn_mfma_f32_16x16x32_bf16(av[ks], bv, acc_s[t], 0, 0, 0);
            else
                acc_u[t] = __builtin_amdgcn_mfma_f32_16x16x32_bf16(av[ks], bv, acc_u[t], 0, 0, 0);
        }
    }
    int rbase = node0 + wave * 16 + q * 4;
#pragma unroll
    for (int r = 0; r < 4; r++) {
        int row = rbase + r;
        if (row < N) {
            float dv = dinv[row];
            float rd = 1.0f / dv;
            float s = SCALE_OUT ? dv : 1.0f;
#pragma unroll
            for (int t = 0; t < 4; t++) {
                float y = fmaf(rd, acc_s[t][r], acc_u[t][r]) + b[t * 16 + n16];
                y = fmaxf(y, 0.0f);
                Yb[(size_t)row * 64 + t * 16 + n16] = f2bf(s * y);
            }
        }
    }
}

// ---------- fused cheb layer-2 + MLP head (LDS-staged; smem reused for Hs) ----------
__global__ __launch_bounds__(256, 4) void k_cheb_mlp(
    const ushort_t* __restrict__ X0, const ushort_t* __restrict__ X1,
    const ushort_t* __restrict__ X2, const float* __restrict__ dinv,
    const ushort_t* __restrict__ Wt, const float* __restrict__ b,
    const ushort_t* __restrict__ Wm1t, const float* __restrict__ bm1,
    const ushort_t* __restrict__ Wm2t, const float* __restrict__ bm2,
    float* __restrict__ out, int N) {
    __shared__ ushort_t smem[3 * 64 * 72];  // 27648 B; XA first, then reused as Hs0/Hs1
    ushort_t (*XA)[64][72] = (ushort_t(*)[64][72])smem;
    ushort_t (*Hs0)[76] = (ushort_t(*)[76])smem;               // [64][76]
    ushort_t (*Hs1)[76] = (ushort_t(*)[76])(smem + 64 * 76);   // [64][76]
    int tid = threadIdx.x;
    int node0 = blockIdx.x * 64;
    const ushort_t* Xc[3] = {X0, X1, X2};
#pragma unroll
    for (int c = 0; c < 3; c++) {
#pragma unroll
        for (int p = 0; p < 2; p++) {
            int s = p * 2048 + tid * 8;
            int row = s >> 6, cc = s & 63;
            v8s v = *(const v8s*)&Xc[c][((size_t)(node0 + row)) * 64 + cc];
            *(v8s*)&XA[c][row][cc] = v;
        }
    }
    __syncthreads();

    int wave = tid >> 6, lane = tid & 63;
    int n16 = lane & 15, q = lane >> 4;
    int lrow = wave * 16 + n16;
    v8s av[6];
#pragma unroll
    for (int ks = 0; ks < 6; ks++)
        av[ks] = *(const v8s*)&XA[ks >> 1][lrow][(ks & 1) * 32 + q * 8];
    __syncthreads();  // all waves done reading XA before Hs0 overwrites it

    // --- cheb GEMM (SCALE_OUT=false) ---
    v4f acc_s[4], acc_u[4];
#pragma unroll
    for (int t = 0; t < 4; t++) {
        acc_s[t] = (v4f){0.f, 0.f, 0.f, 0.f};
        acc_u[t] = (v4f){0.f, 0.f, 0.f, 0.f};
    }
#pragma unroll
    for (int ks = 0; ks < 6; ks++) {
        int c = ks >> 1;
#pragma unroll
        for (int t = 0; t < 4; t++) {
            v8s bv = *(const v8s*)&Wt[(size_t)(t * 16 + n16) * 192 + ks * 32 + q * 8];
            if (c < 2)
                acc_s[t] = __builtin_amdgcn_mfma_f32_16x16x32_bf16(av[ks], bv, acc_s[t], 0, 0, 0);
            else
                acc_u[t] = __builtin_amdgcn_mfma_f32_16x16x32_bf16(av[ks], bv, acc_u[t], 0, 0, 0);
        }
    }
    int lr = wave * 16 + q * 4;
    int rbase = node0 + lr;
#pragma unroll
    for (int r = 0; r < 4; r++) {
        int row = rbase + r;
        if (row < N) {
            float dv = dinv[row];
            float rd = 1.0f / dv;
#pragma unroll
            for (int t = 0; t < 4; t++) {
                float y = fmaf(rd, acc_s[t][r], acc_u[t][r]) + b[t * 16 + n16];
                Hs0[lr + r][t * 16 + n16] = f2bf(fmaxf(y, 0.0f));
            }
        } else {
#pragma unroll
            for (int t = 0; t < 4; t++) Hs0[lr + r][t * 16 + n16] = 0;
        }
    }
    __syncthreads();

    // --- MLP GEMM 1 (64->64, relu) ---
    v4f acc[4];
#pragma unroll
    for (int t = 0; t < 4; t++) acc[t] = (v4f){0.f, 0.f, 0.f, 0.f};
#pragma unroll
    for (int ks = 0; ks < 2; ks++) {
        v8s av1 = *(const v8s*)&Hs0[wave * 16 + n16][ks * 32 + q * 8];
#pragma unroll
        for (int t = 0; t < 4; t++) {
            v8s bv = *(const v8s*)&Wm1t[(size_t)(t * 16 + n16) * 64 + ks * 32 + q * 8];
            acc[t] = __builtin_amdgcn_mfma_f32_16x16x32_bf16(av1, bv, acc[t], 0, 0, 0);
        }
    }
#pragma unroll
    for (int r = 0; r < 4; r++)
#pragma unroll
        for (int t = 0; t < 4; t++) {
            float y = acc[t][r] + bm1[t * 16 + n16];
            Hs1[lr + r][t * 16 + n16] = f2bf(fmaxf(y, 0.0f));
        }
    __syncthreads();

    // --- MLP GEMM 2 (64->32) ---
    v4f a2[2];
    a2[0] = (v4f){0.f, 0.f, 0.f, 0.f};
    a2[1] = (v4f){0.f, 0.f, 0.f, 0.f};
#pragma unroll
    for (int ks = 0; ks < 2; ks++) {
        v8s av2 = *(const v8s*)&Hs1[wave * 16 + n16][ks * 32 + q * 8];
#pragma unroll
        for (int t = 0; t < 2; t++) {
            v8s bv = *(const v8s*)&Wm2t[(size_t)(t * 16 + n16) * 64 + ks * 32 + q * 8];
            a2[t] = __builtin_amdgcn_mfma_f32_16x16x32_bf16(av2, bv, a2[t], 0, 0, 0);
        }
    }
#pragma unroll
    for (int r = 0; r < 4; r++) {
        int row = rbase + r;
        if (row < N) {
#pragma unroll
            for (int t = 0; t < 2; t++)
                out[(size_t)row * 32 + t * 16 + n16] = a2[t][r] + bm2[t * 16 + n16];
        }
    }
}

extern "C" void kernel_launch(void* const* d_in, const int* in_sizes, int n_in,
                              void* d_out, int out_size, void* d_ws, size_t ws_size,
                              hipStream_t stream) {
    const float* features = (const float*)d_in[0];
    const int* src = (const int*)d_in[1];
    const int* dst = (const int*)d_in[2];
    const float* W1 = (const float*)d_in[4];
    const float* b1 = (const float*)d_in[5];
    const float* W2 = (const float*)d_in[6];
    const float* b2 = (const float*)d_in[7];
    const float* Wm1 = (const float*)d_in[8];
    const float* bm1 = (const float*)d_in[9];
    const float* Wm2 = (const float*)d_in[10];
    const float* bm2 = (const float*)d_in[11];
    float* out = (float*)d_out;

    int N = in_sizes[0] / 64;
    int E = in_sizes[1];
    int NB = (N + BSZ - 1) >> BSH;

    float* ws = (float*)d_ws;
    float* dinv = ws;                           // [N]
    int* row_ptr = (int*)(dinv + N);            // [N+1]
    int* gbase = row_ptr + (N + 1);             // [1024]
    int* gcur = gbase + 1024;                   // [1024]
    int* done = gcur + 1024;                    // [16]
    int* col = done + 16;                       // [E]
    int2* eb = (int2*)(((uintptr_t)(col + E) + 7) & ~(uintptr_t)7);  // [E]
    ushort_t* Fb  = (ushort_t*)(eb + E);        // [N*64] scaled
    ushort_t* X1b = Fb  + (size_t)N * 64;       // scaled
    ushort_t* X2b = X1b + (size_t)N * 64;       // unscaled
    ushort_t* H1b = X2b + (size_t)N * 64;       // scaled
    ushort_t* W1t = H1b + (size_t)N * 64;       // [64*192]
    ushort_t* W2t = W1t + 64 * 192;
    ushort_t* Wm1t = W2t + 64 * 192;            // [64*64]
    ushort_t* Wm2t = Wm1t + 64 * 64;            // [32*64]

    int pblk = (N * 64 + 255) / 256;
    int gblk = (N + 63) / 64;
    int n4 = N * 16;
    int cblk = (n4 + 255) / 256;
    int bblk = (E + CHUNK - 1) / CHUNK;

    // weight prep + gbase/done zeroing (one dispatch)
    k_wprep<<<(30720 + 1024 + 255) / 256, 256, 0, stream>>>(
        W1, W2, Wm1, Wm2, W1t, W2t, Wm1t, Wm2t, gbase, done, NB);

    // CSR build (hist+scan fused, then bucket sort)
    k_bhist<<<512, 256, 0, stream>>>(dst, gbase, gcur, done, E, NB);
    k_bucket2<<<bblk, 256, 0, stream>>>(src, dst, gcur, eb, E, NB);
    k_local<<<NB, 256, 0, stream>>>(eb, gbase, col, row_ptr, dinv, N, E, NB);

    // scaled bf16 shadow of features (wide grid)
    k_tobf16<<<cblk, 256, 0, stream>>>((const float4*)features, dinv, (ushort4*)Fb, n4);

    // layer 1
    k_prop<1><<<pblk, 256, 0, stream>>>(Fb, row_ptr, col, dinv, nullptr, X1b, N);
    k_prop<2><<<pblk, 256, 0, stream>>>(X1b, row_ptr, col, dinv, Fb, X2b, N);
    k_cheb_mfma<true><<<gblk, 256, 0, stream>>>(Fb, X1b, X2b, dinv, W1t, b1, H1b, N);

    // layer 2 + MLP head (fused epilogue)
    k_prop<1><<<pblk, 256, 0, stream>>>(H1b, row_ptr, col, dinv, nullptr, X1b, N);
    k_prop<2><<<pblk, 256, 0, stream>>>(X1b, row_ptr, col, dinv, H1b, X2b, N);
    k_cheb_mlp<<<gblk, 256, 0, stream>>>(H1b, X1b, X2b, dinv, W2t, b2,
                                         Wm1t, bm1, Wm2t, bm2, out, N);
}

// Round 6
// 398.878 us; speedup vs baseline: 1.0092x; 1.0092x over previous
//
#include <hip/hip_runtime.h>

// ChebNet round 21: row-local fusion. prop<2> computes X2[n] per node, and the
// cheb GEMM + MLP head need only node-local rows -> fuse prop<2>+cheb1 (k_pc1)
// and prop<2>+cheb2+MLP (k_pc2). Block = 64 nodes, 512 thr (8 waves), wave
// gathers 8 nodes sequentially (same inner loop as k_prop), X2 rows -> 9.2KB
// LDS tile, barrier, MFMA epilogue (fragment split 2 ways: wave w -> rows
// (w>>1)*16, cols (w&1)*32). X2b round-trip eliminated (-25.6MB HBM), 2
// dispatches + gaps removed. launch_bounds(512,8) forces <=64 VGPR so 4 blk/CU
// x 8 waves = 32 waves/CU (full gather parallelism; R20's occupancy trap
// avoided). Discriminates GEMM-anomaly: per-kernel overhead -> vanishes;
// intrinsic -> reappears inside pc kernels. p1 props + CSR byte-identical.

typedef unsigned short ushort_t;
typedef __attribute__((ext_vector_type(8))) short v8s;
typedef __attribute__((ext_vector_type(4))) float v4f;

__device__ inline ushort_t f2bf(float f) {  // RNE float->bf16
    unsigned u = __float_as_uint(f);
    return (ushort_t)((u + 0x7FFFu + ((u >> 16) & 1u)) >> 16);
}
__device__ inline float bf2f(ushort_t h) {
    return __uint_as_float(((unsigned)h) << 16);
}

#define BSH 9
#define BSZ (1 << BSH)
#define CHUNK 4096

// ---------- weight prep + gbase/done zeroing (one dispatch) ----------
__global__ void k_wprep(const float* __restrict__ W1, const float* __restrict__ W2,
                        const float* __restrict__ Wm1, const float* __restrict__ Wm2,
                        ushort_t* __restrict__ W1t, ushort_t* __restrict__ W2t,
                        ushort_t* __restrict__ Wm1t, ushort_t* __restrict__ Wm2t,
                        int* __restrict__ gbase, int* __restrict__ done, int NB) {
    int i = blockIdx.x * 256 + threadIdx.x;
    if (i < 12288) { int k = i >> 6, n = i & 63; W1t[n * 192 + k] = f2bf(W1[i]); return; }
    i -= 12288;
    if (i < 12288) { int k = i >> 6, n = i & 63; W2t[n * 192 + k] = f2bf(W2[i]); return; }
    i -= 12288;
    if (i < 4096) { int k = i >> 6, n = i & 63; Wm1t[n * 64 + k] = f2bf(Wm1[i]); return; }
    i -= 4096;
    if (i < 2048) { int k = i >> 5, n = i & 31; Wm2t[n * 64 + k] = f2bf(Wm2[i]); return; }
    i -= 2048;
    if (i < NB) gbase[i] = 0;
    if (i == NB) *done = 0;
}

// ---------- CSR build: hist + fused scan (last-block ticket, R20-proven) ----------
__global__ __launch_bounds__(256) void k_bhist(const int* __restrict__ dst,
                                               int* __restrict__ gbase,
                                               int* __restrict__ gcur,
                                               int* __restrict__ done, int E, int NB) {
    __shared__ int h[1024];
    __shared__ int isLast;
    for (int i = threadIdx.x; i < NB; i += 256) h[i] = 0;
    __syncthreads();
    for (int i = blockIdx.x * blockDim.x + threadIdx.x; i < E; i += gridDim.x * blockDim.x)
        atomicAdd(&h[dst[i] >> BSH], 1);
    __syncthreads();
    for (int i = threadIdx.x; i < NB; i += 256)
        if (h[i]) atomicAdd(&gbase[i], h[i]);
    __threadfence();
    __syncthreads();
    if (threadIdx.x == 0) isLast = (atomicAdd(done, 1) == (int)gridDim.x - 1);
    __syncthreads();
    if (isLast) {
        __threadfence();
        int t = threadIdx.x;
        int v = (t < NB) ? gbase[t] : 0;  // NB (=196) <= 256
        h[t] = v;
        __syncthreads();
        for (int off = 1; off < 256; off <<= 1) {
            int u = (t >= off) ? h[t - off] : 0;
            __syncthreads();
            h[t] += u;
            __syncthreads();
        }
        if (t < NB) {
            int excl = h[t] - v;
            gbase[t] = excl;
            gcur[t] = excl;
        }
    }
}

__global__ __launch_bounds__(256) void k_bucket2(
    const int* __restrict__ src, const int* __restrict__ dst,
    int* __restrict__ gcur, int2* __restrict__ eb, int E, int NB) {
    __shared__ int ls[CHUNK];
    __shared__ int ld[CHUNK];
    __shared__ int hist[1024];
    __shared__ int bbase[1024];
    int t = threadIdx.x;
    int base = blockIdx.x * CHUNK;
    int count = E - base;
    if (count > CHUNK) count = CHUNK;
    for (int i = t; i < NB; i += 256) hist[i] = 0;
    __syncthreads();
    for (int i = t; i < count; i += 256) {
        int s = src[base + i];
        int d = dst[base + i];
        ls[i] = s;
        ld[i] = d;
        atomicAdd(&hist[d >> BSH], 1);
    }
    __syncthreads();
    for (int b = t; b < NB; b += 256) {
        int c = hist[b];
        bbase[b] = c ? atomicAdd(&gcur[b], c) : 0;
        hist[b] = 0;
    }
    __syncthreads();
    for (int i = t; i < count; i += 256) {
        int d = ld[i];
        int b = d >> BSH;
        int off = atomicAdd(&hist[b], 1);
        eb[bbase[b] + off] = make_int2(ls[i], d);
    }
}

__global__ __launch_bounds__(256) void k_local(
    const int2* __restrict__ eb, const int* __restrict__ gbase,
    int* __restrict__ col, int* __restrict__ row_ptr,
    float* __restrict__ dinv, int N, int E, int NB) {
    __shared__ int cnt[BSZ];
    __shared__ int tsum[256];
    int t = threadIdx.x;
    int b = blockIdx.x;
    int d0 = b << BSH;
    cnt[2 * t] = 0;
    cnt[2 * t + 1] = 0;
    __syncthreads();
    int beg = gbase[b];
    int end = (b + 1 < NB) ? gbase[b + 1] : E;
    for (int i = beg + t; i < end; i += 256)
        atomicAdd(&cnt[eb[i].y - d0], 1);
    __syncthreads();
    int c0 = cnt[2 * t], c1 = cnt[2 * t + 1];
    int mysum = c0 + c1;
    tsum[t] = mysum;
    __syncthreads();
    for (int off = 1; off < 256; off <<= 1) {
        int u = 0;
        if (t >= off) u = tsum[t - off];
        __syncthreads();
        tsum[t] += u;
        __syncthreads();
    }
    int rbase = beg + tsum[t] - mysum;
    int d = d0 + 2 * t;
    if (d < N) {
        row_ptr[d] = rbase;
        dinv[d] = rsqrtf(fmaxf((float)c0, 1.0f));
    }
    if (d + 1 < N) {
        row_ptr[d + 1] = rbase + c0;
        dinv[d + 1] = rsqrtf(fmaxf((float)c1, 1.0f));
    }
    cnt[2 * t] = rbase;
    cnt[2 * t + 1] = rbase + c0;
    __syncthreads();
    for (int i = beg + t; i < end; i += 256) {
        int2 e = eb[i];
        int p = atomicAdd(&cnt[e.y - d0], 1);
        col[p] = e.x;
    }
    if (b == NB - 1 && t == 0) row_ptr[N] = E;
}

// ---------- fp32 -> scaled bf16 shadow (standalone, wide grid) ----------
__global__ void k_tobf16(const float4* __restrict__ X, const float* __restrict__ dinv,
                         ushort4* __restrict__ Y, int n4) {
    int i = blockIdx.x * blockDim.x + threadIdx.x;
    if (i < n4) {
        float s = dinv[i >> 4];
        float4 v = X[i];
        ushort4 o;
        o.x = f2bf(v.x * s); o.y = f2bf(v.y * s); o.z = f2bf(v.z * s); o.w = f2bf(v.w * s);
        Y[i] = o;
    }
}

// ---------- wave-wide gather of one node's 64-feat neighbor sum ----------
// 4 groups of 16 lanes; group g covers edges == g (mod 4); after the two
// shfl_xor reductions every lane holds the full sum (g==0 lanes consume it).
__device__ inline float4 gather_sum(const ushort_t* __restrict__ Xb,
                                    const int* __restrict__ col,
                                    int beg, int end, int g, int fl) {
    float4 a0 = make_float4(0.f, 0.f, 0.f, 0.f);
    float4 a1 = make_float4(0.f, 0.f, 0.f, 0.f);
    int e = beg + g;
    for (; e + 4 < end; e += 8) {
        int s0 = col[e], s1 = col[e + 4];
        ushort4 u0 = *(const ushort4*)&Xb[(size_t)s0 * 64 + fl];
        ushort4 u1 = *(const ushort4*)&Xb[(size_t)s1 * 64 + fl];
        a0.x += bf2f(u0.x); a0.y += bf2f(u0.y); a0.z += bf2f(u0.z); a0.w += bf2f(u0.w);
        a1.x += bf2f(u1.x); a1.y += bf2f(u1.y); a1.z += bf2f(u1.z); a1.w += bf2f(u1.w);
    }
    if (e < end) {
        int s0 = col[e];
        ushort4 u0 = *(const ushort4*)&Xb[(size_t)s0 * 64 + fl];
        a0.x += bf2f(u0.x); a0.y += bf2f(u0.y); a0.z += bf2f(u0.z); a0.w += bf2f(u0.w);
    }
    float4 acc;
    acc.x = a0.x + a1.x; acc.y = a0.y + a1.y;
    acc.z = a0.z + a1.z; acc.w = a0.w + a1.w;
    acc.x += __shfl_xor(acc.x, 16); acc.y += __shfl_xor(acc.y, 16);
    acc.z += __shfl_xor(acc.z, 16); acc.w += __shfl_xor(acc.w, 16);
    acc.x += __shfl_xor(acc.x, 32); acc.y += __shfl_xor(acc.y, 32);
    acc.z += __shfl_xor(acc.z, 32); acc.w += __shfl_xor(acc.w, 32);
    return acc;
}

// ---------- propagation MODE1 (unchanged, pinned at fabric ceiling: CONTROL) ----------
template <int MODE>
__global__ __launch_bounds__(256) void k_prop(
    const ushort_t* __restrict__ Xb, const int* __restrict__ rp,
    const int* __restrict__ col, const float* __restrict__ dinv,
    const ushort_t* __restrict__ X0b, ushort_t* __restrict__ OUTB, int N) {
    int wid = (blockIdx.x * blockDim.x + threadIdx.x) >> 6;
    int lane = threadIdx.x & 63;
    if (wid >= N) return;
    int g = lane >> 4;
    int fl = (lane & 15) * 4;
    int beg = rp[wid], end = rp[wid + 1];
    float4 a0 = make_float4(0.f, 0.f, 0.f, 0.f);
    float4 a1 = make_float4(0.f, 0.f, 0.f, 0.f);
    int e = beg + g;
    for (; e + 4 < end; e += 8) {
        int s0 = col[e], s1 = col[e + 4];
        ushort4 u0 = *(const ushort4*)&Xb[(size_t)s0 * 64 + fl];
        ushort4 u1 = *(const ushort4*)&Xb[(size_t)s1 * 64 + fl];
        a0.x += bf2f(u0.x); a0.y += bf2f(u0.y); a0.z += bf2f(u0.z); a0.w += bf2f(u0.w);
        a1.x += bf2f(u1.x); a1.y += bf2f(u1.y); a1.z += bf2f(u1.z); a1.w += bf2f(u1.w);
    }
    if (e < end) {
        int s0 = col[e];
        ushort4 u0 = *(const ushort4*)&Xb[(size_t)s0 * 64 + fl];
        a0.x += bf2f(u0.x); a0.y += bf2f(u0.y); a0.z += bf2f(u0.z); a0.w += bf2f(u0.w);
    }
    float4 acc;
    acc.x = a0.x + a1.x;
    acc.y = a0.y + a1.y;
    acc.z = a0.z + a1.z;
    acc.w = a0.w + a1.w;
    acc.x += __shfl_xor(acc.x, 16);
    acc.y += __shfl_xor(acc.y, 16);
    acc.z += __shfl_xor(acc.z, 16);
    acc.w += __shfl_xor(acc.w, 16);
    acc.x += __shfl_xor(acc.x, 32);
    acc.y += __shfl_xor(acc.y, 32);
    acc.z += __shfl_xor(acc.z, 32);
    acc.w += __shfl_xor(acc.w, 32);
    if (g == 0) {
        float di = dinv[wid];
        ushort4 ob;
        if (MODE == 1) {
            float m = -di * di;
            ob.x = f2bf(m * acc.x);
            ob.y = f2bf(m * acc.y);
            ob.z = f2bf(m * acc.z);
            ob.w = f2bf(m * acc.w);
        } else {
            ushort4 x0u = *(const ushort4*)&X0b[(size_t)wid * 64 + fl];
            float m = -2.0f * di;
            float rd = 1.0f / di;
            ob.x = f2bf(fmaf(m, acc.x, -rd * bf2f(x0u.x)));
            ob.y = f2bf(fmaf(m, acc.y, -rd * bf2f(x0u.y)));
            ob.z = f2bf(fmaf(m, acc.z, -rd * bf2f(x0u.z)));
            ob.w = f2bf(fmaf(m, acc.w, -rd * bf2f(x0u.w)));
        }
        *(ushort4*)&OUTB[(size_t)wid * 64 + fl] = ob;
    }
}

// ---------- fused prop<2> + cheb GEMM, layer 1 -> H1b (scaled, relu) ----------
// T0 = Fb (scaled X0). Xb = X1b (scaled X1). X2 computed here, kept in LDS.
__global__ __launch_bounds__(512, 8) void k_pc1(
    const ushort_t* __restrict__ Xb, const int* __restrict__ rp,
    const int* __restrict__ col, const float* __restrict__ dinv,
    const ushort_t* __restrict__ T0, const ushort_t* __restrict__ Wt,
    const float* __restrict__ b, ushort_t* __restrict__ Yb, int N) {
    __shared__ ushort_t XA[64][72];
    int tid = threadIdx.x;
    int w = tid >> 6, lane = tid & 63;
    int g = lane >> 4, fl = (lane & 15) * 4;
    int node0 = blockIdx.x * 64;

    // gather phase: wave w -> nodes node0 + w*8 .. +7 (sequential)
    for (int i = 0; i < 8; i++) {
        int nd = node0 + w * 8 + i;
        ushort4 ob;
        ob.x = 0; ob.y = 0; ob.z = 0; ob.w = 0;
        if (nd < N) {
            float4 acc = gather_sum(Xb, col, rp[nd], rp[nd + 1], g, fl);
            if (g == 0) {
                float di = dinv[nd];
                ushort4 x0u = *(const ushort4*)&T0[(size_t)nd * 64 + fl];
                float m = -2.0f * di;
                float rd = 1.0f / di;
                ob.x = f2bf(fmaf(m, acc.x, -rd * bf2f(x0u.x)));
                ob.y = f2bf(fmaf(m, acc.y, -rd * bf2f(x0u.y)));
                ob.z = f2bf(fmaf(m, acc.z, -rd * bf2f(x0u.z)));
                ob.w = f2bf(fmaf(m, acc.w, -rd * bf2f(x0u.w)));
            }
        }
        if (g == 0) *(ushort4*)&XA[w * 8 + i][fl] = ob;
    }
    __syncthreads();

    // MFMA phase: wave w -> row fragment f = w>>1, col half h = w&1
    int n16 = lane & 15, q = lane >> 4;
    int f = w >> 1, h = w & 1;
    int arow = node0 + f * 16 + n16;

    v4f acc_s[2], acc_u[2];
    acc_s[0] = (v4f){0.f, 0.f, 0.f, 0.f};
    acc_s[1] = (v4f){0.f, 0.f, 0.f, 0.f};
    acc_u[0] = (v4f){0.f, 0.f, 0.f, 0.f};
    acc_u[1] = (v4f){0.f, 0.f, 0.f, 0.f};
#pragma unroll
    for (int ks = 0; ks < 6; ks++) {
        int c = ks >> 1;
        int kk = (ks & 1) * 32 + q * 8;
        v8s av = {0, 0, 0, 0, 0, 0, 0, 0};
        if (c == 2) {
            av = *(const v8s*)&XA[f * 16 + n16][kk];
        } else {
            const ushort_t* P = (c == 0) ? T0 : Xb;
            if (arow < N) av = *(const v8s*)&P[(size_t)arow * 64 + kk];
        }
#pragma unroll
        for (int t2 = 0; t2 < 2; t2++) {
            int t = h * 2 + t2;
            v8s bv = *(const v8s*)&Wt[(size_t)(t * 16 + n16) * 192 + ks * 32 + q * 8];
            if (c < 2)
                acc_s[t2] = __builtin_amdgcn_mfma_f32_16x16x32_bf16(av, bv, acc_s[t2], 0, 0, 0);
            else
                acc_u[t2] = __builtin_amdgcn_mfma_f32_16x16x32_bf16(av, bv, acc_u[t2], 0, 0, 0);
        }
    }
    int rbase = node0 + f * 16 + q * 4;
#pragma unroll
    for (int r = 0; r < 4; r++) {
        int row = rbase + r;
        if (row < N) {
            float dv = dinv[row];
            float rd = 1.0f / dv;
#pragma unroll
            for (int t2 = 0; t2 < 2; t2++) {
                int t = h * 2 + t2;
                float y = fmaf(rd, acc_s[t2][r], acc_u[t2][r]) + b[t * 16 + n16];
                y = fmaxf(y, 0.0f);
                Yb[(size_t)row * 64 + t * 16 + n16] = f2bf(dv * y);
            }
        }
    }
}

// ---------- fused prop<2> + cheb GEMM + MLP head, layer 2 -> out ----------
// T0 = H1b (scaled). Xb = X1b (scaled). LDS: XA (X2) then reused as Hs0/Hs1.
__global__ __launch_bounds__(512, 8) void k_pc2(
    const ushort_t* __restrict__ Xb, const int* __restrict__ rp,
    const int* __restrict__ col, const float* __restrict__ dinv,
    const ushort_t* __restrict__ T0, const ushort_t* __restrict__ Wt,
    const float* __restrict__ b,
    const ushort_t* __restrict__ Wm1t, const float* __restrict__ bm1,
    const ushort_t* __restrict__ Wm2t, const float* __restrict__ bm2,
    float* __restrict__ out, int N) {
    __shared__ ushort_t smem[9728];  // 19456 B
    ushort_t (*XA)[72] = (ushort_t(*)[72])smem;                // [64][72]
    ushort_t (*Hs0)[76] = (ushort_t(*)[76])smem;               // [64][76]
    ushort_t (*Hs1)[76] = (ushort_t(*)[76])(smem + 64 * 76);   // [64][76]
    int tid = threadIdx.x;
    int w = tid >> 6, lane = tid & 63;
    int g = lane >> 4, fl = (lane & 15) * 4;
    int node0 = blockIdx.x * 64;

    for (int i = 0; i < 8; i++) {
        int nd = node0 + w * 8 + i;
        ushort4 ob;
        ob.x = 0; ob.y = 0; ob.z = 0; ob.w = 0;
        if (nd < N) {
            float4 acc = gather_sum(Xb, col, rp[nd], rp[nd + 1], g, fl);
            if (g == 0) {
                float di = dinv[nd];
                ushort4 x0u = *(const ushort4*)&T0[(size_t)nd * 64 + fl];
                float m = -2.0f * di;
                float rd = 1.0f / di;
                ob.x = f2bf(fmaf(m, acc.x, -rd * bf2f(x0u.x)));
                ob.y = f2bf(fmaf(m, acc.y, -rd * bf2f(x0u.y)));
                ob.z = f2bf(fmaf(m, acc.z, -rd * bf2f(x0u.z)));
                ob.w = f2bf(fmaf(m, acc.w, -rd * bf2f(x0u.w)));
            }
        }
        if (g == 0) *(ushort4*)&XA[w * 8 + i][fl] = ob;
    }
    __syncthreads();

    int n16 = lane & 15, q = lane >> 4;
    int f = w >> 1, h = w & 1;
    int arow = node0 + f * 16 + n16;

    // X2 fragments out of XA BEFORE smem is reused as Hs0
    v8s av4 = *(const v8s*)&XA[f * 16 + n16][q * 8];
    v8s av5 = *(const v8s*)&XA[f * 16 + n16][32 + q * 8];
    __syncthreads();  // all waves done reading XA; Hs0 may overwrite

    // --- cheb GEMM ---
    v4f acc_s[2], acc_u[2];
    acc_s[0] = (v4f){0.f, 0.f, 0.f, 0.f};
    acc_s[1] = (v4f){0.f, 0.f, 0.f, 0.f};
    acc_u[0] = (v4f){0.f, 0.f, 0.f, 0.f};
    acc_u[1] = (v4f){0.f, 0.f, 0.f, 0.f};
#pragma unroll
    for (int ks = 0; ks < 6; ks++) {
        int c = ks >> 1;
        int kk = (ks & 1) * 32 + q * 8;
        v8s av;
        if (c == 2) {
            av = (ks & 1) ? av5 : av4;
        } else {
            const ushort_t* P = (c == 0) ? T0 : Xb;
            av = (v8s){0, 0, 0, 0, 0, 0, 0, 0};
            if (arow < N) av = *(const v8s*)&P[(size_t)arow * 64 + kk];
        }
#pragma unroll
        for (int t2 = 0; t2 < 2; t2++) {
            int t = h * 2 + t2;
            v8s bv = *(const v8s*)&Wt[(size_t)(t * 16 + n16) * 192 + ks * 32 + q * 8];
            if (c < 2)
                acc_s[t2] = __builtin_amdgcn_mfma_f32_16x16x32_bf16(av, bv, acc_s[t2], 0, 0, 0);
            else
                acc_u[t2] = __builtin_amdgcn_mfma_f32_16x16x32_bf16(av, bv, acc_u[t2], 0, 0, 0);
        }
    }
    int lr = f * 16 + q * 4;
    int rbase = node0 + lr;
#pragma unroll
    for (int r = 0; r < 4; r++) {
        int row = rbase + r;
        if (row < N) {
            float dv = dinv[row];
            float rd = 1.0f / dv;
#pragma unroll
            for (int t2 = 0; t2 < 2; t2++) {
                int t = h * 2 + t2;
                float y = fmaf(rd, acc_s[t2][r], acc_u[t2][r]) + b[t * 16 + n16];
                Hs0[lr + r][t * 16 + n16] = f2bf(fmaxf(y, 0.0f));
            }
        } else {
#pragma unroll
            for (int t2 = 0; t2 < 2; t2++)
                Hs0[lr + r][(h * 2 + t2) * 16 + n16] = 0;
        }
    }
    __syncthreads();

    // --- MLP GEMM 1 (64->64, relu) ---
    v4f acc[2];
    acc[0] = (v4f){0.f, 0.f, 0.f, 0.f};
    acc[1] = (v4f){0.f, 0.f, 0.f, 0.f};
#pragma unroll
    for (int ks = 0; ks < 2; ks++) {
        v8s av1 = *(const v8s*)&Hs0[f * 16 + n16][ks * 32 + q * 8];
#pragma unroll
        for (int t2 = 0; t2 < 2; t2++) {
            int t = h * 2 + t2;
            v8s bv = *(const v8s*)&Wm1t[(size_t)(t * 16 + n16) * 64 + ks * 32 + q * 8];
            acc[t2] = __builtin_amdgcn_mfma_f32_16x16x32_bf16(av1, bv, acc[t2], 0, 0, 0);
        }
    }
#pragma unroll
    for (int r = 0; r < 4; r++)
#pragma unroll
        for (int t2 = 0; t2 < 2; t2++) {
            int t = h * 2 + t2;
            float y = acc[t2][r] + bm1[t * 16 + n16];
            Hs1[lr + r][t * 16 + n16] = f2bf(fmaxf(y, 0.0f));
        }
    __syncthreads();

    // --- MLP GEMM 2 (64->32): wave half h handles output cols h*16.. ---
    v4f a2 = (v4f){0.f, 0.f, 0.f, 0.f};
#pragma unroll
    for (int ks = 0; ks < 2; ks++) {
        v8s av2 = *(const v8s*)&Hs1[f * 16 + n16][ks * 32 + q * 8];
        v8s bv = *(const v8s*)&Wm2t[(size_t)(h * 16 + n16) * 64 + ks * 32 + q * 8];
        a2 = __builtin_amdgcn_mfma_f32_16x16x32_bf16(av2, bv, a2, 0, 0, 0);
    }
#pragma unroll
    for (int r = 0; r < 4; r++) {
        int row = rbase + r;
        if (row < N)
            out[(size_t)row * 32 + h * 16 + n16] = a2[r] + bm2[h * 16 + n16];
    }
}

extern "C" void kernel_launch(void* const* d_in, const int* in_sizes, int n_in,
                              void* d_out, int out_size, void* d_ws, size_t ws_size,
                              hipStream_t stream) {
    const float* features = (const float*)d_in[0];
    const int* src = (const int*)d_in[1];
    const int* dst = (const int*)d_in[2];
    const float* W1 = (const float*)d_in[4];
    const float* b1 = (const float*)d_in[5];
    const float* W2 = (const float*)d_in[6];
    const float* b2 = (const float*)d_in[7];
    const float* Wm1 = (const float*)d_in[8];
    const float* bm1 = (const float*)d_in[9];
    const float* Wm2 = (const float*)d_in[10];
    const float* bm2 = (const float*)d_in[11];
    float* out = (float*)d_out;

    int N = in_sizes[0] / 64;
    int E = in_sizes[1];
    int NB = (N + BSZ - 1) >> BSH;

    float* ws = (float*)d_ws;
    float* dinv = ws;                           // [N]
    int* row_ptr = (int*)(dinv + N);            // [N+1]
    int* gbase = row_ptr + (N + 1);             // [1024]
    int* gcur = gbase + 1024;                   // [1024]
    int* done = gcur + 1024;                    // [16]
    int* col = done + 16;                       // [E]
    int2* eb = (int2*)(((uintptr_t)(col + E) + 7) & ~(uintptr_t)7);  // [E]
    ushort_t* Fb  = (ushort_t*)(eb + E);        // [N*64] scaled X0
    ushort_t* X1b = Fb  + (size_t)N * 64;       // scaled X1
    ushort_t* H1b = X1b + (size_t)N * 64;       // scaled H1
    ushort_t* W1t = H1b + (size_t)N * 64;       // [64*192]
    ushort_t* W2t = W1t + 64 * 192;
    ushort_t* Wm1t = W2t + 64 * 192;            // [64*64]
    ushort_t* Wm2t = Wm1t + 64 * 64;            // [32*64]

    int pblk = (N * 64 + 255) / 256;
    int gblk = (N + 63) / 64;
    int n4 = N * 16;
    int cblk = (n4 + 255) / 256;
    int bblk = (E + CHUNK - 1) / CHUNK;

    // weight prep + gbase/done zeroing
    k_wprep<<<(30720 + 1024 + 255) / 256, 256, 0, stream>>>(
        W1, W2, Wm1, Wm2, W1t, W2t, Wm1t, Wm2t, gbase, done, NB);

    // CSR build
    k_bhist<<<512, 256, 0, stream>>>(dst, gbase, gcur, done, E, NB);
    k_bucket2<<<bblk, 256, 0, stream>>>(src, dst, gcur, eb, E, NB);
    k_local<<<NB, 256, 0, stream>>>(eb, gbase, col, row_ptr, dinv, N, E, NB);

    // scaled bf16 shadow of features
    k_tobf16<<<cblk, 256, 0, stream>>>((const float4*)features, dinv, (ushort4*)Fb, n4);

    // layer 1: prop<1>, then fused prop<2>+cheb
    k_prop<1><<<pblk, 256, 0, stream>>>(Fb, row_ptr, col, dinv, nullptr, X1b, N);
    k_pc1<<<gblk, 512, 0, stream>>>(X1b, row_ptr, col, dinv, Fb, W1t, b1, H1b, N);

    // layer 2: prop<1>, then fused prop<2>+cheb+MLP
    k_prop<1><<<pblk, 256, 0, stream>>>(H1b, row_ptr, col, dinv, nullptr, X1b, N);
    k_pc2<<<gblk, 512, 0, stream>>>(X1b, row_ptr, col, dinv, H1b, W2t, b2,
                                    Wm1t, bm1, Wm2t, bm2, out, N);
}

// Round 7
// 380.087 us; speedup vs baseline: 1.0590x; 1.0494x over previous
//
#include <hip/hip_runtime.h>

// ChebNet round 22: (1) REVERT the R20 bhist+bscan ticket fusion — ledger
// attribution across R20 (+15.8) and R21 (+12.2) pins its cost at ~+20us:
// 512x256 device-scope __threadfence (L2 writeback across 8 non-coherent XCD
// L2s) >> the 3us dispatch gap it saved. Separate bhist/bscan restored
// (R15/R18 measured-good). (2) KEEP pc fusion: k_pc2=83.6 < prop2+cheb_mlp=
// 86.8, FETCH 113<127.2 MB. (3) Preload the 8 rp (beg,end) pairs per wave
// before the gather loop — in R21 they serialized each node's gather
// (1.54 vs 2.80 TB/s); full unroll keeps indices compile-time (no scratch).

typedef unsigned short ushort_t;
typedef __attribute__((ext_vector_type(8))) short v8s;
typedef __attribute__((ext_vector_type(4))) float v4f;

__device__ inline ushort_t f2bf(float f) {  // RNE float->bf16
    unsigned u = __float_as_uint(f);
    return (ushort_t)((u + 0x7FFFu + ((u >> 16) & 1u)) >> 16);
}
__device__ inline float bf2f(ushort_t h) {
    return __uint_as_float(((unsigned)h) << 16);
}

#define BSH 9
#define BSZ (1 << BSH)
#define CHUNK 4096

// ---------- weight prep + gbase zeroing (one dispatch) ----------
__global__ void k_wprep(const float* __restrict__ W1, const float* __restrict__ W2,
                        const float* __restrict__ Wm1, const float* __restrict__ Wm2,
                        ushort_t* __restrict__ W1t, ushort_t* __restrict__ W2t,
                        ushort_t* __restrict__ Wm1t, ushort_t* __restrict__ Wm2t,
                        int* __restrict__ gbase, int NB) {
    int i = blockIdx.x * 256 + threadIdx.x;
    if (i < 12288) { int k = i >> 6, n = i & 63; W1t[n * 192 + k] = f2bf(W1[i]); return; }
    i -= 12288;
    if (i < 12288) { int k = i >> 6, n = i & 63; W2t[n * 192 + k] = f2bf(W2[i]); return; }
    i -= 12288;
    if (i < 4096) { int k = i >> 6, n = i & 63; Wm1t[n * 64 + k] = f2bf(Wm1[i]); return; }
    i -= 4096;
    if (i < 2048) { int k = i >> 5, n = i & 31; Wm2t[n * 64 + k] = f2bf(Wm2[i]); return; }
    i -= 2048;
    if (i < NB) gbase[i] = 0;
}

// ---------- CSR build (R15/R18 measured-good: separate hist + scan) ----------

__global__ __launch_bounds__(256) void k_bhist(const int* __restrict__ dst,
                                               int* __restrict__ gbase, int E, int NB) {
    __shared__ int h[1024];
    for (int i = threadIdx.x; i < NB; i += 256) h[i] = 0;
    __syncthreads();
    for (int i = blockIdx.x * blockDim.x + threadIdx.x; i < E; i += gridDim.x * blockDim.x)
        atomicAdd(&h[dst[i] >> BSH], 1);
    __syncthreads();
    for (int i = threadIdx.x; i < NB; i += 256)
        if (h[i]) atomicAdd(&gbase[i], h[i]);
}

__global__ void k_bscan(int* __restrict__ gbase, int* __restrict__ gcur, int NB) {
    __shared__ int sh[1024];
    int t = threadIdx.x;
    int v = (t < NB) ? gbase[t] : 0;
    sh[t] = v;
    __syncthreads();
    for (int off = 1; off < 1024; off <<= 1) {
        int u = 0;
        if (t >= off) u = sh[t - off];
        __syncthreads();
        sh[t] += u;
        __syncthreads();
    }
    if (t < NB) {
        int excl = sh[t] - v;
        gbase[t] = excl;
        gcur[t] = excl;
    }
}

__global__ __launch_bounds__(256) void k_bucket2(
    const int* __restrict__ src, const int* __restrict__ dst,
    int* __restrict__ gcur, int2* __restrict__ eb, int E, int NB) {
    __shared__ int ls[CHUNK];
    __shared__ int ld[CHUNK];
    __shared__ int hist[1024];
    __shared__ int bbase[1024];
    int t = threadIdx.x;
    int base = blockIdx.x * CHUNK;
    int count = E - base;
    if (count > CHUNK) count = CHUNK;
    for (int i = t; i < NB; i += 256) hist[i] = 0;
    __syncthreads();
    for (int i = t; i < count; i += 256) {
        int s = src[base + i];
        int d = dst[base + i];
        ls[i] = s;
        ld[i] = d;
        atomicAdd(&hist[d >> BSH], 1);
    }
    __syncthreads();
    for (int b = t; b < NB; b += 256) {
        int c = hist[b];
        bbase[b] = c ? atomicAdd(&gcur[b], c) : 0;
        hist[b] = 0;
    }
    __syncthreads();
    for (int i = t; i < count; i += 256) {
        int d = ld[i];
        int b = d >> BSH;
        int off = atomicAdd(&hist[b], 1);
        eb[bbase[b] + off] = make_int2(ls[i], d);
    }
}

__global__ __launch_bounds__(256) void k_local(
    const int2* __restrict__ eb, const int* __restrict__ gbase,
    int* __restrict__ col, int* __restrict__ row_ptr,
    float* __restrict__ dinv, int N, int E, int NB) {
    __shared__ int cnt[BSZ];
    __shared__ int tsum[256];
    int t = threadIdx.x;
    int b = blockIdx.x;
    int d0 = b << BSH;
    cnt[2 * t] = 0;
    cnt[2 * t + 1] = 0;
    __syncthreads();
    int beg = gbase[b];
    int end = (b + 1 < NB) ? gbase[b + 1] : E;
    for (int i = beg + t; i < end; i += 256)
        atomicAdd(&cnt[eb[i].y - d0], 1);
    __syncthreads();
    int c0 = cnt[2 * t], c1 = cnt[2 * t + 1];
    int mysum = c0 + c1;
    tsum[t] = mysum;
    __syncthreads();
    for (int off = 1; off < 256; off <<= 1) {
        int u = 0;
        if (t >= off) u = tsum[t - off];
        __syncthreads();
        tsum[t] += u;
        __syncthreads();
    }
    int rbase = beg + tsum[t] - mysum;
    int d = d0 + 2 * t;
    if (d < N) {
        row_ptr[d] = rbase;
        dinv[d] = rsqrtf(fmaxf((float)c0, 1.0f));
    }
    if (d + 1 < N) {
        row_ptr[d + 1] = rbase + c0;
        dinv[d + 1] = rsqrtf(fmaxf((float)c1, 1.0f));
    }
    cnt[2 * t] = rbase;
    cnt[2 * t + 1] = rbase + c0;
    __syncthreads();
    for (int i = beg + t; i < end; i += 256) {
        int2 e = eb[i];
        int p = atomicAdd(&cnt[e.y - d0], 1);
        col[p] = e.x;
    }
    if (b == NB - 1 && t == 0) row_ptr[N] = E;
}

// ---------- fp32 -> scaled bf16 shadow (standalone, wide grid) ----------
__global__ void k_tobf16(const float4* __restrict__ X, const float* __restrict__ dinv,
                         ushort4* __restrict__ Y, int n4) {
    int i = blockIdx.x * blockDim.x + threadIdx.x;
    if (i < n4) {
        float s = dinv[i >> 4];
        float4 v = X[i];
        ushort4 o;
        o.x = f2bf(v.x * s); o.y = f2bf(v.y * s); o.z = f2bf(v.z * s); o.w = f2bf(v.w * s);
        Y[i] = o;
    }
}

// ---------- wave-wide gather of one node's 64-feat neighbor sum ----------
__device__ inline float4 gather_sum(const ushort_t* __restrict__ Xb,
                                    const int* __restrict__ col,
                                    int beg, int end, int g, int fl) {
    float4 a0 = make_float4(0.f, 0.f, 0.f, 0.f);
    float4 a1 = make_float4(0.f, 0.f, 0.f, 0.f);
    int e = beg + g;
    for (; e + 4 < end; e += 8) {
        int s0 = col[e], s1 = col[e + 4];
        ushort4 u0 = *(const ushort4*)&Xb[(size_t)s0 * 64 + fl];
        ushort4 u1 = *(const ushort4*)&Xb[(size_t)s1 * 64 + fl];
        a0.x += bf2f(u0.x); a0.y += bf2f(u0.y); a0.z += bf2f(u0.z); a0.w += bf2f(u0.w);
        a1.x += bf2f(u1.x); a1.y += bf2f(u1.y); a1.z += bf2f(u1.z); a1.w += bf2f(u1.w);
    }
    if (e < end) {
        int s0 = col[e];
        ushort4 u0 = *(const ushort4*)&Xb[(size_t)s0 * 64 + fl];
        a0.x += bf2f(u0.x); a0.y += bf2f(u0.y); a0.z += bf2f(u0.z); a0.w += bf2f(u0.w);
    }
    float4 acc;
    acc.x = a0.x + a1.x; acc.y = a0.y + a1.y;
    acc.z = a0.z + a1.z; acc.w = a0.w + a1.w;
    acc.x += __shfl_xor(acc.x, 16); acc.y += __shfl_xor(acc.y, 16);
    acc.z += __shfl_xor(acc.z, 16); acc.w += __shfl_xor(acc.w, 16);
    acc.x += __shfl_xor(acc.x, 32); acc.y += __shfl_xor(acc.y, 32);
    acc.z += __shfl_xor(acc.z, 32); acc.w += __shfl_xor(acc.w, 32);
    return acc;
}

// ---------- propagation MODE1 (unchanged, pinned at fabric ceiling: CONTROL) ----------
template <int MODE>
__global__ __launch_bounds__(256) void k_prop(
    const ushort_t* __restrict__ Xb, const int* __restrict__ rp,
    const int* __restrict__ col, const float* __restrict__ dinv,
    const ushort_t* __restrict__ X0b, ushort_t* __restrict__ OUTB, int N) {
    int wid = (blockIdx.x * blockDim.x + threadIdx.x) >> 6;
    int lane = threadIdx.x & 63;
    if (wid >= N) return;
    int g = lane >> 4;
    int fl = (lane & 15) * 4;
    int beg = rp[wid], end = rp[wid + 1];
    float4 a0 = make_float4(0.f, 0.f, 0.f, 0.f);
    float4 a1 = make_float4(0.f, 0.f, 0.f, 0.f);
    int e = beg + g;
    for (; e + 4 < end; e += 8) {
        int s0 = col[e], s1 = col[e + 4];
        ushort4 u0 = *(const ushort4*)&Xb[(size_t)s0 * 64 + fl];
        ushort4 u1 = *(const ushort4*)&Xb[(size_t)s1 * 64 + fl];
        a0.x += bf2f(u0.x); a0.y += bf2f(u0.y); a0.z += bf2f(u0.z); a0.w += bf2f(u0.w);
        a1.x += bf2f(u1.x); a1.y += bf2f(u1.y); a1.z += bf2f(u1.z); a1.w += bf2f(u1.w);
    }
    if (e < end) {
        int s0 = col[e];
        ushort4 u0 = *(const ushort4*)&Xb[(size_t)s0 * 64 + fl];
        a0.x += bf2f(u0.x); a0.y += bf2f(u0.y); a0.z += bf2f(u0.z); a0.w += bf2f(u0.w);
    }
    float4 acc;
    acc.x = a0.x + a1.x;
    acc.y = a0.y + a1.y;
    acc.z = a0.z + a1.z;
    acc.w = a0.w + a1.w;
    acc.x += __shfl_xor(acc.x, 16);
    acc.y += __shfl_xor(acc.y, 16);
    acc.z += __shfl_xor(acc.z, 16);
    acc.w += __shfl_xor(acc.w, 16);
    acc.x += __shfl_xor(acc.x, 32);
    acc.y += __shfl_xor(acc.y, 32);
    acc.z += __shfl_xor(acc.z, 32);
    acc.w += __shfl_xor(acc.w, 32);
    if (g == 0) {
        float di = dinv[wid];
        ushort4 ob;
        if (MODE == 1) {
            float m = -di * di;
            ob.x = f2bf(m * acc.x);
            ob.y = f2bf(m * acc.y);
            ob.z = f2bf(m * acc.z);
            ob.w = f2bf(m * acc.w);
        } else {
            ushort4 x0u = *(const ushort4*)&X0b[(size_t)wid * 64 + fl];
            float m = -2.0f * di;
            float rd = 1.0f / di;
            ob.x = f2bf(fmaf(m, acc.x, -rd * bf2f(x0u.x)));
            ob.y = f2bf(fmaf(m, acc.y, -rd * bf2f(x0u.y)));
            ob.z = f2bf(fmaf(m, acc.z, -rd * bf2f(x0u.z)));
            ob.w = f2bf(fmaf(m, acc.w, -rd * bf2f(x0u.w)));
        }
        *(ushort4*)&OUTB[(size_t)wid * 64 + fl] = ob;
    }
}

// ---------- fused prop<2> + cheb GEMM, layer 1 -> H1b (scaled, relu) ----------
__global__ __launch_bounds__(512, 8) void k_pc1(
    const ushort_t* __restrict__ Xb, const int* __restrict__ rp,
    const int* __restrict__ col, const float* __restrict__ dinv,
    const ushort_t* __restrict__ T0, const ushort_t* __restrict__ Wt,
    const float* __restrict__ b, ushort_t* __restrict__ Yb, int N) {
    __shared__ ushort_t XA[64][72];
    int tid = threadIdx.x;
    int w = tid >> 6, lane = tid & 63;
    int g = lane >> 4, fl = (lane & 15) * 4;
    int node0 = blockIdx.x * 64;

    // preload all 8 rp pairs (independent loads, off the per-node critical path)
    int begs[8], ends[8];
#pragma unroll
    for (int i = 0; i < 8; i++) {
        int nd = node0 + w * 8 + i;
        begs[i] = (nd < N) ? rp[nd] : 0;
        ends[i] = (nd < N) ? rp[nd + 1] : 0;
    }

    // gather phase: wave w -> nodes node0 + w*8 .. +7
#pragma unroll
    for (int i = 0; i < 8; i++) {
        int nd = node0 + w * 8 + i;
        ushort4 ob;
        ob.x = 0; ob.y = 0; ob.z = 0; ob.w = 0;
        if (nd < N) {
            float4 acc = gather_sum(Xb, col, begs[i], ends[i], g, fl);
            if (g == 0) {
                float di = dinv[nd];
                ushort4 x0u = *(const ushort4*)&T0[(size_t)nd * 64 + fl];
                float m = -2.0f * di;
                float rd = 1.0f / di;
                ob.x = f2bf(fmaf(m, acc.x, -rd * bf2f(x0u.x)));
                ob.y = f2bf(fmaf(m, acc.y, -rd * bf2f(x0u.y)));
                ob.z = f2bf(fmaf(m, acc.z, -rd * bf2f(x0u.z)));
                ob.w = f2bf(fmaf(m, acc.w, -rd * bf2f(x0u.w)));
            }
        }
        if (g == 0) *(ushort4*)&XA[w * 8 + i][fl] = ob;
    }
    __syncthreads();

    // MFMA phase: wave w -> row fragment f = w>>1, col half h = w&1
    int n16 = lane & 15, q = lane >> 4;
    int f = w >> 1, h = w & 1;
    int arow = node0 + f * 16 + n16;

    v4f acc_s[2], acc_u[2];
    acc_s[0] = (v4f){0.f, 0.f, 0.f, 0.f};
    acc_s[1] = (v4f){0.f, 0.f, 0.f, 0.f};
    acc_u[0] = (v4f){0.f, 0.f, 0.f, 0.f};
    acc_u[1] = (v4f){0.f, 0.f, 0.f, 0.f};
#pragma unroll
    for (int ks = 0; ks < 6; ks++) {
        int c = ks >> 1;
        int kk = (ks & 1) * 32 + q * 8;
        v8s av = {0, 0, 0, 0, 0, 0, 0, 0};
        if (c == 2) {
            av = *(const v8s*)&XA[f * 16 + n16][kk];
        } else {
            const ushort_t* P = (c == 0) ? T0 : Xb;
            if (arow < N) av = *(const v8s*)&P[(size_t)arow * 64 + kk];
        }
#pragma unroll
        for (int t2 = 0; t2 < 2; t2++) {
            int t = h * 2 + t2;
            v8s bv = *(const v8s*)&Wt[(size_t)(t * 16 + n16) * 192 + ks * 32 + q * 8];
            if (c < 2)
                acc_s[t2] = __builtin_amdgcn_mfma_f32_16x16x32_bf16(av, bv, acc_s[t2], 0, 0, 0);
            else
                acc_u[t2] = __builtin_amdgcn_mfma_f32_16x16x32_bf16(av, bv, acc_u[t2], 0, 0, 0);
        }
    }
    int rbase = node0 + f * 16 + q * 4;
#pragma unroll
    for (int r = 0; r < 4; r++) {
        int row = rbase + r;
        if (row < N) {
            float dv = dinv[row];
            float rd = 1.0f / dv;
#pragma unroll
            for (int t2 = 0; t2 < 2; t2++) {
                int t = h * 2 + t2;
                float y = fmaf(rd, acc_s[t2][r], acc_u[t2][r]) + b[t * 16 + n16];
                y = fmaxf(y, 0.0f);
                Yb[(size_t)row * 64 + t * 16 + n16] = f2bf(dv * y);
            }
        }
    }
}

// ---------- fused prop<2> + cheb GEMM + MLP head, layer 2 -> out ----------
__global__ __launch_bounds__(512, 8) void k_pc2(
    const ushort_t* __restrict__ Xb, const int* __restrict__ rp,
    const int* __restrict__ col, const float* __restrict__ dinv,
    const ushort_t* __restrict__ T0, const ushort_t* __restrict__ Wt,
    const float* __restrict__ b,
    const ushort_t* __restrict__ Wm1t, const float* __restrict__ bm1,
    const ushort_t* __restrict__ Wm2t, const float* __restrict__ bm2,
    float* __restrict__ out, int N) {
    __shared__ ushort_t smem[9728];  // 19456 B
    ushort_t (*XA)[72] = (ushort_t(*)[72])smem;                // [64][72]
    ushort_t (*Hs0)[76] = (ushort_t(*)[76])smem;               // [64][76]
    ushort_t (*Hs1)[76] = (ushort_t(*)[76])(smem + 64 * 76);   // [64][76]
    int tid = threadIdx.x;
    int w = tid >> 6, lane = tid & 63;
    int g = lane >> 4, fl = (lane & 15) * 4;
    int node0 = blockIdx.x * 64;

    int begs[8], ends[8];
#pragma unroll
    for (int i = 0; i < 8; i++) {
        int nd = node0 + w * 8 + i;
        begs[i] = (nd < N) ? rp[nd] : 0;
        ends[i] = (nd < N) ? rp[nd + 1] : 0;
    }

#pragma unroll
    for (int i = 0; i < 8; i++) {
        int nd = node0 + w * 8 + i;
        ushort4 ob;
        ob.x = 0; ob.y = 0; ob.z = 0; ob.w = 0;
        if (nd < N) {
            float4 acc = gather_sum(Xb, col, begs[i], ends[i], g, fl);
            if (g == 0) {
                float di = dinv[nd];
                ushort4 x0u = *(const ushort4*)&T0[(size_t)nd * 64 + fl];
                float m = -2.0f * di;
                float rd = 1.0f / di;
                ob.x = f2bf(fmaf(m, acc.x, -rd * bf2f(x0u.x)));
                ob.y = f2bf(fmaf(m, acc.y, -rd * bf2f(x0u.y)));
                ob.z = f2bf(fmaf(m, acc.z, -rd * bf2f(x0u.z)));
                ob.w = f2bf(fmaf(m, acc.w, -rd * bf2f(x0u.w)));
            }
        }
        if (g == 0) *(ushort4*)&XA[w * 8 + i][fl] = ob;
    }
    __syncthreads();

    int n16 = lane & 15, q = lane >> 4;
    int f = w >> 1, h = w & 1;
    int arow = node0 + f * 16 + n16;

    // X2 fragments out of XA BEFORE smem is reused as Hs0
    v8s av4 = *(const v8s*)&XA[f * 16 + n16][q * 8];
    v8s av5 = *(const v8s*)&XA[f * 16 + n16][32 + q * 8];
    __syncthreads();  // all waves done reading XA; Hs0 may overwrite

    // --- cheb GEMM ---
    v4f acc_s[2], acc_u[2];
    acc_s[0] = (v4f){0.f, 0.f, 0.f, 0.f};
    acc_s[1] = (v4f){0.f, 0.f, 0.f, 0.f};
    acc_u[0] = (v4f){0.f, 0.f, 0.f, 0.f};
    acc_u[1] = (v4f){0.f, 0.f, 0.f, 0.f};
#pragma unroll
    for (int ks = 0; ks < 6; ks++) {
        int c = ks >> 1;
        int kk = (ks & 1) * 32 + q * 8;
        v8s av;
        if (c == 2) {
            av = (ks & 1) ? av5 : av4;
        } else {
            const ushort_t* P = (c == 0) ? T0 : Xb;
            av = (v8s){0, 0, 0, 0, 0, 0, 0, 0};
            if (arow < N) av = *(const v8s*)&P[(size_t)arow * 64 + kk];
        }
#pragma unroll
        for (int t2 = 0; t2 < 2; t2++) {
            int t = h * 2 + t2;
            v8s bv = *(const v8s*)&Wt[(size_t)(t * 16 + n16) * 192 + ks * 32 + q * 8];
            if (c < 2)
                acc_s[t2] = __builtin_amdgcn_mfma_f32_16x16x32_bf16(av, bv, acc_s[t2], 0, 0, 0);
            else
                acc_u[t2] = __builtin_amdgcn_mfma_f32_16x16x32_bf16(av, bv, acc_u[t2], 0, 0, 0);
        }
    }
    int lr = f * 16 + q * 4;
    int rbase = node0 + lr;
#pragma unroll
    for (int r = 0; r < 4; r++) {
        int row = rbase + r;
        if (row < N) {
            float dv = dinv[row];
            float rd = 1.0f / dv;
#pragma unroll
            for (int t2 = 0; t2 < 2; t2++) {
                int t = h * 2 + t2;
                float y = fmaf(rd, acc_s[t2][r], acc_u[t2][r]) + b[t * 16 + n16];
                Hs0[lr + r][t * 16 + n16] = f2bf(fmaxf(y, 0.0f));
            }
        } else {
#pragma unroll
            for (int t2 = 0; t2 < 2; t2++)
                Hs0[lr + r][(h * 2 + t2) * 16 + n16] = 0;
        }
    }
    __syncthreads();

    // --- MLP GEMM 1 (64->64, relu) ---
    v4f acc[2];
    acc[0] = (v4f){0.f, 0.f, 0.f, 0.f};
    acc[1] = (v4f){0.f, 0.f, 0.f, 0.f};
#pragma unroll
    for (int ks = 0; ks < 2; ks++) {
        v8s av1 = *(const v8s*)&Hs0[f * 16 + n16][ks * 32 + q * 8];
#pragma unroll
        for (int t2 = 0; t2 < 2; t2++) {
            int t = h * 2 + t2;
            v8s bv = *(const v8s*)&Wm1t[(size_t)(t * 16 + n16) * 64 + ks * 32 + q * 8];
            acc[t2] = __builtin_amdgcn_mfma_f32_16x16x32_bf16(av1, bv, acc[t2], 0, 0, 0);
        }
    }
#pragma unroll
    for (int r = 0; r < 4; r++)
#pragma unroll
        for (int t2 = 0; t2 < 2; t2++) {
            int t = h * 2 + t2;
            float y = acc[t2][r] + bm1[t * 16 + n16];
            Hs1[lr + r][t * 16 + n16] = f2bf(fmaxf(y, 0.0f));
        }
    __syncthreads();

    // --- MLP GEMM 2 (64->32): wave half h handles output cols h*16.. ---
    v4f a2 = (v4f){0.f, 0.f, 0.f, 0.f};
#pragma unroll
    for (int ks = 0; ks < 2; ks++) {
        v8s av2 = *(const v8s*)&Hs1[f * 16 + n16][ks * 32 + q * 8];
        v8s bv = *(const v8s*)&Wm2t[(size_t)(h * 16 + n16) * 64 + ks * 32 + q * 8];
        a2 = __builtin_amdgcn_mfma_f32_16x16x32_bf16(av2, bv, a2, 0, 0, 0);
    }
#pragma unroll
    for (int r = 0; r < 4; r++) {
        int row = rbase + r;
        if (row < N)
            out[(size_t)row * 32 + h * 16 + n16] = a2[r] + bm2[h * 16 + n16];
    }
}

extern "C" void kernel_launch(void* const* d_in, const int* in_sizes, int n_in,
                              void* d_out, int out_size, void* d_ws, size_t ws_size,
                              hipStream_t stream) {
    const float* features = (const float*)d_in[0];
    const int* src = (const int*)d_in[1];
    const int* dst = (const int*)d_in[2];
    const float* W1 = (const float*)d_in[4];
    const float* b1 = (const float*)d_in[5];
    const float* W2 = (const float*)d_in[6];
    const float* b2 = (const float*)d_in[7];
    const float* Wm1 = (const float*)d_in[8];
    const float* bm1 = (const float*)d_in[9];
    const float* Wm2 = (const float*)d_in[10];
    const float* bm2 = (const float*)d_in[11];
    float* out = (float*)d_out;

    int N = in_sizes[0] / 64;
    int E = in_sizes[1];
    int NB = (N + BSZ - 1) >> BSH;

    float* ws = (float*)d_ws;
    float* dinv = ws;                           // [N]
    int* row_ptr = (int*)(dinv + N);            // [N+1]
    int* gbase = row_ptr + (N + 1);             // [1024]
    int* gcur = gbase + 1024;                   // [1024]
    int* col = gcur + 1024;                     // [E]
    int2* eb = (int2*)(((uintptr_t)(col + E) + 7) & ~(uintptr_t)7);  // [E]
    ushort_t* Fb  = (ushort_t*)(eb + E);        // [N*64] scaled X0
    ushort_t* X1b = Fb  + (size_t)N * 64;       // scaled X1
    ushort_t* H1b = X1b + (size_t)N * 64;       // scaled H1
    ushort_t* W1t = H1b + (size_t)N * 64;       // [64*192]
    ushort_t* W2t = W1t + 64 * 192;
    ushort_t* Wm1t = W2t + 64 * 192;            // [64*64]
    ushort_t* Wm2t = Wm1t + 64 * 64;            // [32*64]

    int pblk = (N * 64 + 255) / 256;
    int gblk = (N + 63) / 64;
    int n4 = N * 16;
    int cblk = (n4 + 255) / 256;
    int bblk = (E + CHUNK - 1) / CHUNK;

    // weight prep + gbase zeroing
    k_wprep<<<(30720 + 1024 + 255) / 256, 256, 0, stream>>>(
        W1, W2, Wm1, Wm2, W1t, W2t, Wm1t, Wm2t, gbase, NB);

    // CSR build (separate hist + scan: R18 measured-good)
    k_bhist<<<512, 256, 0, stream>>>(dst, gbase, E, NB);
    k_bscan<<<1, 1024, 0, stream>>>(gbase, gcur, NB);
    k_bucket2<<<bblk, 256, 0, stream>>>(src, dst, gcur, eb, E, NB);
    k_local<<<NB, 256, 0, stream>>>(eb, gbase, col, row_ptr, dinv, N, E, NB);

    // scaled bf16 shadow of features
    k_tobf16<<<cblk, 256, 0, stream>>>((const float4*)features, dinv, (ushort4*)Fb, n4);

    // layer 1: prop<1>, then fused prop<2>+cheb
    k_prop<1><<<pblk, 256, 0, stream>>>(Fb, row_ptr, col, dinv, nullptr, X1b, N);
    k_pc1<<<gblk, 512, 0, stream>>>(X1b, row_ptr, col, dinv, Fb, W1t, b1, H1b, N);

    // layer 2: prop<1>, then fused prop<2>+cheb+MLP
    k_prop<1><<<pblk, 256, 0, stream>>>(H1b, row_ptr, col, dinv, nullptr, X1b, N);
    k_pc2<<<gblk, 512, 0, stream>>>(X1b, row_ptr, col, dinv, H1b, W2t, b2,
                                    Wm1t, bm1, Wm2t, bm2, out, N);
}

// Round 8
// 373.180 us; speedup vs baseline: 1.0786x; 1.0185x over previous
//
#include <hip/hip_runtime.h>

// ChebNet round 23: pc-kernel scheduling granularity. R22 ledger: k_pc2 = 83.6us
// @1.53 TB/s vs k_prop 44.2 @2.80 on the same gather work. Theory: 1563x8-wave
// blocks at 4 blocks/CU = TWO quantized rounds + per-block barrier convoy ->
// effective gather concurrency ~halved (R17 standalone showed same 34%-occupancy
// tail signature). Fix: 32-node/256-thread pc tiles -> 3125 blocks, 8 blocks/CU,
// ~12 retire-and-replace rounds (the k_prop regime). LDS <=9.7KB, N%32==0.
// Everything else byte-identical to R22 (controls: k_prop, CSR, tobf16).

typedef unsigned short ushort_t;
typedef __attribute__((ext_vector_type(8))) short v8s;
typedef __attribute__((ext_vector_type(4))) float v4f;

__device__ inline ushort_t f2bf(float f) {  // RNE float->bf16
    unsigned u = __float_as_uint(f);
    return (ushort_t)((u + 0x7FFFu + ((u >> 16) & 1u)) >> 16);
}
__device__ inline float bf2f(ushort_t h) {
    return __uint_as_float(((unsigned)h) << 16);
}

#define BSH 9
#define BSZ (1 << BSH)
#define CHUNK 4096

// ---------- weight prep + gbase zeroing (one dispatch) ----------
__global__ void k_wprep(const float* __restrict__ W1, const float* __restrict__ W2,
                        const float* __restrict__ Wm1, const float* __restrict__ Wm2,
                        ushort_t* __restrict__ W1t, ushort_t* __restrict__ W2t,
                        ushort_t* __restrict__ Wm1t, ushort_t* __restrict__ Wm2t,
                        int* __restrict__ gbase, int NB) {
    int i = blockIdx.x * 256 + threadIdx.x;
    if (i < 12288) { int k = i >> 6, n = i & 63; W1t[n * 192 + k] = f2bf(W1[i]); return; }
    i -= 12288;
    if (i < 12288) { int k = i >> 6, n = i & 63; W2t[n * 192 + k] = f2bf(W2[i]); return; }
    i -= 12288;
    if (i < 4096) { int k = i >> 6, n = i & 63; Wm1t[n * 64 + k] = f2bf(Wm1[i]); return; }
    i -= 4096;
    if (i < 2048) { int k = i >> 5, n = i & 31; Wm2t[n * 64 + k] = f2bf(Wm2[i]); return; }
    i -= 2048;
    if (i < NB) gbase[i] = 0;
}

// ---------- CSR build (R15/R18 measured-good: separate hist + scan) ----------

__global__ __launch_bounds__(256) void k_bhist(const int* __restrict__ dst,
                                               int* __restrict__ gbase, int E, int NB) {
    __shared__ int h[1024];
    for (int i = threadIdx.x; i < NB; i += 256) h[i] = 0;
    __syncthreads();
    for (int i = blockIdx.x * blockDim.x + threadIdx.x; i < E; i += gridDim.x * blockDim.x)
        atomicAdd(&h[dst[i] >> BSH], 1);
    __syncthreads();
    for (int i = threadIdx.x; i < NB; i += 256)
        if (h[i]) atomicAdd(&gbase[i], h[i]);
}

__global__ void k_bscan(int* __restrict__ gbase, int* __restrict__ gcur, int NB) {
    __shared__ int sh[1024];
    int t = threadIdx.x;
    int v = (t < NB) ? gbase[t] : 0;
    sh[t] = v;
    __syncthreads();
    for (int off = 1; off < 1024; off <<= 1) {
        int u = 0;
        if (t >= off) u = sh[t - off];
        __syncthreads();
        sh[t] += u;
        __syncthreads();
    }
    if (t < NB) {
        int excl = sh[t] - v;
        gbase[t] = excl;
        gcur[t] = excl;
    }
}

__global__ __launch_bounds__(256) void k_bucket2(
    const int* __restrict__ src, const int* __restrict__ dst,
    int* __restrict__ gcur, int2* __restrict__ eb, int E, int NB) {
    __shared__ int ls[CHUNK];
    __shared__ int ld[CHUNK];
    __shared__ int hist[1024];
    __shared__ int bbase[1024];
    int t = threadIdx.x;
    int base = blockIdx.x * CHUNK;
    int count = E - base;
    if (count > CHUNK) count = CHUNK;
    for (int i = t; i < NB; i += 256) hist[i] = 0;
    __syncthreads();
    for (int i = t; i < count; i += 256) {
        int s = src[base + i];
        int d = dst[base + i];
        ls[i] = s;
        ld[i] = d;
        atomicAdd(&hist[d >> BSH], 1);
    }
    __syncthreads();
    for (int b = t; b < NB; b += 256) {
        int c = hist[b];
        bbase[b] = c ? atomicAdd(&gcur[b], c) : 0;
        hist[b] = 0;
    }
    __syncthreads();
    for (int i = t; i < count; i += 256) {
        int d = ld[i];
        int b = d >> BSH;
        int off = atomicAdd(&hist[b], 1);
        eb[bbase[b] + off] = make_int2(ls[i], d);
    }
}

__global__ __launch_bounds__(256) void k_local(
    const int2* __restrict__ eb, const int* __restrict__ gbase,
    int* __restrict__ col, int* __restrict__ row_ptr,
    float* __restrict__ dinv, int N, int E, int NB) {
    __shared__ int cnt[BSZ];
    __shared__ int tsum[256];
    int t = threadIdx.x;
    int b = blockIdx.x;
    int d0 = b << BSH;
    cnt[2 * t] = 0;
    cnt[2 * t + 1] = 0;
    __syncthreads();
    int beg = gbase[b];
    int end = (b + 1 < NB) ? gbase[b + 1] : E;
    for (int i = beg + t; i < end; i += 256)
        atomicAdd(&cnt[eb[i].y - d0], 1);
    __syncthreads();
    int c0 = cnt[2 * t], c1 = cnt[2 * t + 1];
    int mysum = c0 + c1;
    tsum[t] = mysum;
    __syncthreads();
    for (int off = 1; off < 256; off <<= 1) {
        int u = 0;
        if (t >= off) u = tsum[t - off];
        __syncthreads();
        tsum[t] += u;
        __syncthreads();
    }
    int rbase = beg + tsum[t] - mysum;
    int d = d0 + 2 * t;
    if (d < N) {
        row_ptr[d] = rbase;
        dinv[d] = rsqrtf(fmaxf((float)c0, 1.0f));
    }
    if (d + 1 < N) {
        row_ptr[d + 1] = rbase + c0;
        dinv[d + 1] = rsqrtf(fmaxf((float)c1, 1.0f));
    }
    cnt[2 * t] = rbase;
    cnt[2 * t + 1] = rbase + c0;
    __syncthreads();
    for (int i = beg + t; i < end; i += 256) {
        int2 e = eb[i];
        int p = atomicAdd(&cnt[e.y - d0], 1);
        col[p] = e.x;
    }
    if (b == NB - 1 && t == 0) row_ptr[N] = E;
}

// ---------- fp32 -> scaled bf16 shadow (standalone, wide grid) ----------
__global__ void k_tobf16(const float4* __restrict__ X, const float* __restrict__ dinv,
                         ushort4* __restrict__ Y, int n4) {
    int i = blockIdx.x * blockDim.x + threadIdx.x;
    if (i < n4) {
        float s = dinv[i >> 4];
        float4 v = X[i];
        ushort4 o;
        o.x = f2bf(v.x * s); o.y = f2bf(v.y * s); o.z = f2bf(v.z * s); o.w = f2bf(v.w * s);
        Y[i] = o;
    }
}

// ---------- wave-wide gather of one node's 64-feat neighbor sum ----------
__device__ inline float4 gather_sum(const ushort_t* __restrict__ Xb,
                                    const int* __restrict__ col,
                                    int beg, int end, int g, int fl) {
    float4 a0 = make_float4(0.f, 0.f, 0.f, 0.f);
    float4 a1 = make_float4(0.f, 0.f, 0.f, 0.f);
    int e = beg + g;
    for (; e + 4 < end; e += 8) {
        int s0 = col[e], s1 = col[e + 4];
        ushort4 u0 = *(const ushort4*)&Xb[(size_t)s0 * 64 + fl];
        ushort4 u1 = *(const ushort4*)&Xb[(size_t)s1 * 64 + fl];
        a0.x += bf2f(u0.x); a0.y += bf2f(u0.y); a0.z += bf2f(u0.z); a0.w += bf2f(u0.w);
        a1.x += bf2f(u1.x); a1.y += bf2f(u1.y); a1.z += bf2f(u1.z); a1.w += bf2f(u1.w);
    }
    if (e < end) {
        int s0 = col[e];
        ushort4 u0 = *(const ushort4*)&Xb[(size_t)s0 * 64 + fl];
        a0.x += bf2f(u0.x); a0.y += bf2f(u0.y); a0.z += bf2f(u0.z); a0.w += bf2f(u0.w);
    }
    float4 acc;
    acc.x = a0.x + a1.x; acc.y = a0.y + a1.y;
    acc.z = a0.z + a1.z; acc.w = a0.w + a1.w;
    acc.x += __shfl_xor(acc.x, 16); acc.y += __shfl_xor(acc.y, 16);
    acc.z += __shfl_xor(acc.z, 16); acc.w += __shfl_xor(acc.w, 16);
    acc.x += __shfl_xor(acc.x, 32); acc.y += __shfl_xor(acc.y, 32);
    acc.z += __shfl_xor(acc.z, 32); acc.w += __shfl_xor(acc.w, 32);
    return acc;
}

// ---------- propagation MODE1 (unchanged, pinned at fabric ceiling: CONTROL) ----------
template <int MODE>
__global__ __launch_bounds__(256) void k_prop(
    const ushort_t* __restrict__ Xb, const int* __restrict__ rp,
    const int* __restrict__ col, const float* __restrict__ dinv,
    const ushort_t* __restrict__ X0b, ushort_t* __restrict__ OUTB, int N) {
    int wid = (blockIdx.x * blockDim.x + threadIdx.x) >> 6;
    int lane = threadIdx.x & 63;
    if (wid >= N) return;
    int g = lane >> 4;
    int fl = (lane & 15) * 4;
    int beg = rp[wid], end = rp[wid + 1];
    float4 a0 = make_float4(0.f, 0.f, 0.f, 0.f);
    float4 a1 = make_float4(0.f, 0.f, 0.f, 0.f);
    int e = beg + g;
    for (; e + 4 < end; e += 8) {
        int s0 = col[e], s1 = col[e + 4];
        ushort4 u0 = *(const ushort4*)&Xb[(size_t)s0 * 64 + fl];
        ushort4 u1 = *(const ushort4*)&Xb[(size_t)s1 * 64 + fl];
        a0.x += bf2f(u0.x); a0.y += bf2f(u0.y); a0.z += bf2f(u0.z); a0.w += bf2f(u0.w);
        a1.x += bf2f(u1.x); a1.y += bf2f(u1.y); a1.z += bf2f(u1.z); a1.w += bf2f(u1.w);
    }
    if (e < end) {
        int s0 = col[e];
        ushort4 u0 = *(const ushort4*)&Xb[(size_t)s0 * 64 + fl];
        a0.x += bf2f(u0.x); a0.y += bf2f(u0.y); a0.z += bf2f(u0.z); a0.w += bf2f(u0.w);
    }
    float4 acc;
    acc.x = a0.x + a1.x;
    acc.y = a0.y + a1.y;
    acc.z = a0.z + a1.z;
    acc.w = a0.w + a1.w;
    acc.x += __shfl_xor(acc.x, 16);
    acc.y += __shfl_xor(acc.y, 16);
    acc.z += __shfl_xor(acc.z, 16);
    acc.w += __shfl_xor(acc.w, 16);
    acc.x += __shfl_xor(acc.x, 32);
    acc.y += __shfl_xor(acc.y, 32);
    acc.z += __shfl_xor(acc.z, 32);
    acc.w += __shfl_xor(acc.w, 32);
    if (g == 0) {
        float di = dinv[wid];
        ushort4 ob;
        if (MODE == 1) {
            float m = -di * di;
            ob.x = f2bf(m * acc.x);
            ob.y = f2bf(m * acc.y);
            ob.z = f2bf(m * acc.z);
            ob.w = f2bf(m * acc.w);
        } else {
            ushort4 x0u = *(const ushort4*)&X0b[(size_t)wid * 64 + fl];
            float m = -2.0f * di;
            float rd = 1.0f / di;
            ob.x = f2bf(fmaf(m, acc.x, -rd * bf2f(x0u.x)));
            ob.y = f2bf(fmaf(m, acc.y, -rd * bf2f(x0u.y)));
            ob.z = f2bf(fmaf(m, acc.z, -rd * bf2f(x0u.z)));
            ob.w = f2bf(fmaf(m, acc.w, -rd * bf2f(x0u.w)));
        }
        *(ushort4*)&OUTB[(size_t)wid * 64 + fl] = ob;
    }
}

// ---------- fused prop<2> + cheb GEMM, layer 1 -> H1b (scaled, relu) ----------
// R23: 32-node tile, 256 threads (4 waves x 8 nodes). f = w>>1, h = w&1.
__global__ __launch_bounds__(256, 8) void k_pc1(
    const ushort_t* __restrict__ Xb, const int* __restrict__ rp,
    const int* __restrict__ col, const float* __restrict__ dinv,
    const ushort_t* __restrict__ T0, const ushort_t* __restrict__ Wt,
    const float* __restrict__ b, ushort_t* __restrict__ Yb, int N) {
    __shared__ ushort_t XA[32][72];
    int tid = threadIdx.x;
    int w = tid >> 6, lane = tid & 63;
    int g = lane >> 4, fl = (lane & 15) * 4;
    int node0 = blockIdx.x * 32;

    int begs[8], ends[8];
#pragma unroll
    for (int i = 0; i < 8; i++) {
        int nd = node0 + w * 8 + i;
        begs[i] = (nd < N) ? rp[nd] : 0;
        ends[i] = (nd < N) ? rp[nd + 1] : 0;
    }

#pragma unroll
    for (int i = 0; i < 8; i++) {
        int nd = node0 + w * 8 + i;
        ushort4 ob;
        ob.x = 0; ob.y = 0; ob.z = 0; ob.w = 0;
        if (nd < N) {
            float4 acc = gather_sum(Xb, col, begs[i], ends[i], g, fl);
            if (g == 0) {
                float di = dinv[nd];
                ushort4 x0u = *(const ushort4*)&T0[(size_t)nd * 64 + fl];
                float m = -2.0f * di;
                float rd = 1.0f / di;
                ob.x = f2bf(fmaf(m, acc.x, -rd * bf2f(x0u.x)));
                ob.y = f2bf(fmaf(m, acc.y, -rd * bf2f(x0u.y)));
                ob.z = f2bf(fmaf(m, acc.z, -rd * bf2f(x0u.z)));
                ob.w = f2bf(fmaf(m, acc.w, -rd * bf2f(x0u.w)));
            }
        }
        if (g == 0) *(ushort4*)&XA[w * 8 + i][fl] = ob;
    }
    __syncthreads();

    // MFMA phase: wave w -> row fragment f = w>>1 (0..1), col half h = w&1
    int n16 = lane & 15, q = lane >> 4;
    int f = w >> 1, h = w & 1;
    int arow = node0 + f * 16 + n16;

    v4f acc_s[2], acc_u[2];
    acc_s[0] = (v4f){0.f, 0.f, 0.f, 0.f};
    acc_s[1] = (v4f){0.f, 0.f, 0.f, 0.f};
    acc_u[0] = (v4f){0.f, 0.f, 0.f, 0.f};
    acc_u[1] = (v4f){0.f, 0.f, 0.f, 0.f};
#pragma unroll
    for (int ks = 0; ks < 6; ks++) {
        int c = ks >> 1;
        int kk = (ks & 1) * 32 + q * 8;
        v8s av = {0, 0, 0, 0, 0, 0, 0, 0};
        if (c == 2) {
            av = *(const v8s*)&XA[f * 16 + n16][kk];
        } else {
            const ushort_t* P = (c == 0) ? T0 : Xb;
            if (arow < N) av = *(const v8s*)&P[(size_t)arow * 64 + kk];
        }
#pragma unroll
        for (int t2 = 0; t2 < 2; t2++) {
            int t = h * 2 + t2;
            v8s bv = *(const v8s*)&Wt[(size_t)(t * 16 + n16) * 192 + ks * 32 + q * 8];
            if (c < 2)
                acc_s[t2] = __builtin_amdgcn_mfma_f32_16x16x32_bf16(av, bv, acc_s[t2], 0, 0, 0);
            else
                acc_u[t2] = __builtin_amdgcn_mfma_f32_16x16x32_bf16(av, bv, acc_u[t2], 0, 0, 0);
        }
    }
    int rbase = node0 + f * 16 + q * 4;
#pragma unroll
    for (int r = 0; r < 4; r++) {
        int row = rbase + r;
        if (row < N) {
            float dv = dinv[row];
            float rd = 1.0f / dv;
#pragma unroll
            for (int t2 = 0; t2 < 2; t2++) {
                int t = h * 2 + t2;
                float y = fmaf(rd, acc_s[t2][r], acc_u[t2][r]) + b[t * 16 + n16];
                y = fmaxf(y, 0.0f);
                Yb[(size_t)row * 64 + t * 16 + n16] = f2bf(dv * y);
            }
        }
    }
}

// ---------- fused prop<2> + cheb GEMM + MLP head, layer 2 -> out ----------
// R23: 32-node tile, 256 threads.
__global__ __launch_bounds__(256, 8) void k_pc2(
    const ushort_t* __restrict__ Xb, const int* __restrict__ rp,
    const int* __restrict__ col, const float* __restrict__ dinv,
    const ushort_t* __restrict__ T0, const ushort_t* __restrict__ Wt,
    const float* __restrict__ b,
    const ushort_t* __restrict__ Wm1t, const float* __restrict__ bm1,
    const ushort_t* __restrict__ Wm2t, const float* __restrict__ bm2,
    float* __restrict__ out, int N) {
    __shared__ ushort_t smem[4864];  // 9728 B: XA[32][72]=2304 then Hs0/Hs1 [32][76]x2
    ushort_t (*XA)[72] = (ushort_t(*)[72])smem;                // [32][72]
    ushort_t (*Hs0)[76] = (ushort_t(*)[76])smem;               // [32][76]
    ushort_t (*Hs1)[76] = (ushort_t(*)[76])(smem + 32 * 76);   // [32][76]
    int tid = threadIdx.x;
    int w = tid >> 6, lane = tid & 63;
    int g = lane >> 4, fl = (lane & 15) * 4;
    int node0 = blockIdx.x * 32;

    int begs[8], ends[8];
#pragma unroll
    for (int i = 0; i < 8; i++) {
        int nd = node0 + w * 8 + i;
        begs[i] = (nd < N) ? rp[nd] : 0;
        ends[i] = (nd < N) ? rp[nd + 1] : 0;
    }

#pragma unroll
    for (int i = 0; i < 8; i++) {
        int nd = node0 + w * 8 + i;
        ushort4 ob;
        ob.x = 0; ob.y = 0; ob.z = 0; ob.w = 0;
        if (nd < N) {
            float4 acc = gather_sum(Xb, col, begs[i], ends[i], g, fl);
            if (g == 0) {
                float di = dinv[nd];
                ushort4 x0u = *(const ushort4*)&T0[(size_t)nd * 64 + fl];
                float m = -2.0f * di;
                float rd = 1.0f / di;
                ob.x = f2bf(fmaf(m, acc.x, -rd * bf2f(x0u.x)));
                ob.y = f2bf(fmaf(m, acc.y, -rd * bf2f(x0u.y)));
                ob.z = f2bf(fmaf(m, acc.z, -rd * bf2f(x0u.z)));
                ob.w = f2bf(fmaf(m, acc.w, -rd * bf2f(x0u.w)));
            }
        }
        if (g == 0) *(ushort4*)&XA[w * 8 + i][fl] = ob;
    }
    __syncthreads();

    int n16 = lane & 15, q = lane >> 4;
    int f = w >> 1, h = w & 1;
    int arow = node0 + f * 16 + n16;

    // X2 fragments out of XA BEFORE smem is reused as Hs0
    v8s av4 = *(const v8s*)&XA[f * 16 + n16][q * 8];
    v8s av5 = *(const v8s*)&XA[f * 16 + n16][32 + q * 8];
    __syncthreads();  // all waves done reading XA; Hs0 may overwrite

    // --- cheb GEMM ---
    v4f acc_s[2], acc_u[2];
    acc_s[0] = (v4f){0.f, 0.f, 0.f, 0.f};
    acc_s[1] = (v4f){0.f, 0.f, 0.f, 0.f};
    acc_u[0] = (v4f){0.f, 0.f, 0.f, 0.f};
    acc_u[1] = (v4f){0.f, 0.f, 0.f, 0.f};
#pragma unroll
    for (int ks = 0; ks < 6; ks++) {
        int c = ks >> 1;
        int kk = (ks & 1) * 32 + q * 8;
        v8s av;
        if (c == 2) {
            av = (ks & 1) ? av5 : av4;
        } else {
            const ushort_t* P = (c == 0) ? T0 : Xb;
            av = (v8s){0, 0, 0, 0, 0, 0, 0, 0};
            if (arow < N) av = *(const v8s*)&P[(size_t)arow * 64 + kk];
        }
#pragma unroll
        for (int t2 = 0; t2 < 2; t2++) {
            int t = h * 2 + t2;
            v8s bv = *(const v8s*)&Wt[(size_t)(t * 16 + n16) * 192 + ks * 32 + q * 8];
            if (c < 2)
                acc_s[t2] = __builtin_amdgcn_mfma_f32_16x16x32_bf16(av, bv, acc_s[t2], 0, 0, 0);
            else
                acc_u[t2] = __builtin_amdgcn_mfma_f32_16x16x32_bf16(av, bv, acc_u[t2], 0, 0, 0);
        }
    }
    int lr = f * 16 + q * 4;
    int rbase = node0 + lr;
#pragma unroll
    for (int r = 0; r < 4; r++) {
        int row = rbase + r;
        if (row < N) {
            float dv = dinv[row];
            float rd = 1.0f / dv;
#pragma unroll
            for (int t2 = 0; t2 < 2; t2++) {
                int t = h * 2 + t2;
                float y = fmaf(rd, acc_s[t2][r], acc_u[t2][r]) + b[t * 16 + n16];
                Hs0[lr + r][t * 16 + n16] = f2bf(fmaxf(y, 0.0f));
            }
        } else {
#pragma unroll
            for (int t2 = 0; t2 < 2; t2++)
                Hs0[lr + r][(h * 2 + t2) * 16 + n16] = 0;
        }
    }
    __syncthreads();

    // --- MLP GEMM 1 (64->64, relu) ---
    v4f acc[2];
    acc[0] = (v4f){0.f, 0.f, 0.f, 0.f};
    acc[1] = (v4f){0.f, 0.f, 0.f, 0.f};
#pragma unroll
    for (int ks = 0; ks < 2; ks++) {
        v8s av1 = *(const v8s*)&Hs0[f * 16 + n16][ks * 32 + q * 8];
#pragma unroll
        for (int t2 = 0; t2 < 2; t2++) {
            int t = h * 2 + t2;
            v8s bv = *(const v8s*)&Wm1t[(size_t)(t * 16 + n16) * 64 + ks * 32 + q * 8];
            acc[t2] = __builtin_amdgcn_mfma_f32_16x16x32_bf16(av1, bv, acc[t2], 0, 0, 0);
        }
    }
#pragma unroll
    for (int r = 0; r < 4; r++)
#pragma unroll
        for (int t2 = 0; t2 < 2; t2++) {
            int t = h * 2 + t2;
            float y = acc[t2][r] + bm1[t * 16 + n16];
            Hs1[lr + r][t * 16 + n16] = f2bf(fmaxf(y, 0.0f));
        }
    __syncthreads();

    // --- MLP GEMM 2 (64->32): wave half h handles output cols h*16.. ---
    v4f a2 = (v4f){0.f, 0.f, 0.f, 0.f};
#pragma unroll
    for (int ks = 0; ks < 2; ks++) {
        v8s av2 = *(const v8s*)&Hs1[f * 16 + n16][ks * 32 + q * 8];
        v8s bv = *(const v8s*)&Wm2t[(size_t)(h * 16 + n16) * 64 + ks * 32 + q * 8];
        a2 = __builtin_amdgcn_mfma_f32_16x16x32_bf16(av2, bv, a2, 0, 0, 0);
    }
#pragma unroll
    for (int r = 0; r < 4; r++) {
        int row = rbase + r;
        if (row < N)
            out[(size_t)row * 32 + h * 16 + n16] = a2[r] + bm2[h * 16 + n16];
    }
}

extern "C" void kernel_launch(void* const* d_in, const int* in_sizes, int n_in,
                              void* d_out, int out_size, void* d_ws, size_t ws_size,
                              hipStream_t stream) {
    const float* features = (const float*)d_in[0];
    const int* src = (const int*)d_in[1];
    const int* dst = (const int*)d_in[2];
    const float* W1 = (const float*)d_in[4];
    const float* b1 = (const float*)d_in[5];
    const float* W2 = (const float*)d_in[6];
    const float* b2 = (const float*)d_in[7];
    const float* Wm1 = (const float*)d_in[8];
    const float* bm1 = (const float*)d_in[9];
    const float* Wm2 = (const float*)d_in[10];
    const float* bm2 = (const float*)d_in[11];
    float* out = (float*)d_out;

    int N = in_sizes[0] / 64;
    int E = in_sizes[1];
    int NB = (N + BSZ - 1) >> BSH;

    float* ws = (float*)d_ws;
    float* dinv = ws;                           // [N]
    int* row_ptr = (int*)(dinv + N);            // [N+1]
    int* gbase = row_ptr + (N + 1);             // [1024]
    int* gcur = gbase + 1024;                   // [1024]
    int* col = gcur + 1024;                     // [E]
    int2* eb = (int2*)(((uintptr_t)(col + E) + 7) & ~(uintptr_t)7);  // [E]
    ushort_t* Fb  = (ushort_t*)(eb + E);        // [N*64] scaled X0
    ushort_t* X1b = Fb  + (size_t)N * 64;       // scaled X1
    ushort_t* H1b = X1b + (size_t)N * 64;       // scaled H1
    ushort_t* W1t = H1b + (size_t)N * 64;       // [64*192]
    ushort_t* W2t = W1t + 64 * 192;
    ushort_t* Wm1t = W2t + 64 * 192;            // [64*64]
    ushort_t* Wm2t = Wm1t + 64 * 64;            // [32*64]

    int pblk = (N * 64 + 255) / 256;
    int gblk32 = (N + 31) / 32;
    int n4 = N * 16;
    int cblk = (n4 + 255) / 256;
    int bblk = (E + CHUNK - 1) / CHUNK;

    // weight prep + gbase zeroing
    k_wprep<<<(30720 + 1024 + 255) / 256, 256, 0, stream>>>(
        W1, W2, Wm1, Wm2, W1t, W2t, Wm1t, Wm2t, gbase, NB);

    // CSR build (separate hist + scan: R18 measured-good)
    k_bhist<<<512, 256, 0, stream>>>(dst, gbase, E, NB);
    k_bscan<<<1, 1024, 0, stream>>>(gbase, gcur, NB);
    k_bucket2<<<bblk, 256, 0, stream>>>(src, dst, gcur, eb, E, NB);
    k_local<<<NB, 256, 0, stream>>>(eb, gbase, col, row_ptr, dinv, N, E, NB);

    // scaled bf16 shadow of features
    k_tobf16<<<cblk, 256, 0, stream>>>((const float4*)features, dinv, (ushort4*)Fb, n4);

    // layer 1: prop<1>, then fused prop<2>+cheb
    k_prop<1><<<pblk, 256, 0, stream>>>(Fb, row_ptr, col, dinv, nullptr, X1b, N);
    k_pc1<<<gblk32, 256, 0, stream>>>(X1b, row_ptr, col, dinv, Fb, W1t, b1, H1b, N);

    // layer 2: prop<1>, then fused prop<2>+cheb+MLP
    k_prop<1><<<pblk, 256, 0, stream>>>(H1b, row_ptr, col, dinv, nullptr, X1b, N);
    k_pc2<<<gblk32, 256, 0, stream>>>(X1b, row_ptr, col, dinv, H1b, W2t, b2,
                                      Wm1t, bm1, Wm2t, bm2, out, N);
}